// Round 5
// baseline (2034.598 us; speedup 1.0000x reference)
//
#include <hip/hip_runtime.h>
#include <hip/hip_bf16.h>

#define B_ 16
#define S_ 2048
#define H_ 1024
#define U_ 512
#define NH 8
#define TOPK 100

#define M_ (B_*S_)      // 32768 rows (b,s)
#define NC (NH*U_)      // 4096 cols (n,u)

typedef short s16x8 __attribute__((ext_vector_type(8)));
typedef float f32x4 __attribute__((ext_vector_type(4)));

__device__ __forceinline__ float fast_tanh(float x) {
    float e = __expf(2.f * x);
    return (e - 1.f) / (e + 1.f);
}

__device__ __forceinline__ unsigned short f2bf(float f) {
    unsigned u = __float_as_uint(f);
    u = u + 0x7fffu + ((u >> 16) & 1u);
    return (unsigned short)(u >> 16);
}

__device__ __forceinline__ void gl16(const unsigned short* g, unsigned short* l) {
    __builtin_amdgcn_global_load_lds(
        (const __attribute__((address_space(1))) void*)g,
        (__attribute__((address_space(3))) void*)l, 16, 0, 0);
}

// ---------------- prep: fp32 -> bf16 hi/lo ----------------
__global__ void convert_A(const float* __restrict__ v,
                          unsigned short* __restrict__ hi,
                          unsigned short* __restrict__ lo) {
    size_t i = ((size_t)blockIdx.x * 256 + threadIdx.x) * 4;
    float4 f = *(const float4*)(v + i);
    float c[4] = {f.x, f.y, f.z, f.w};
    unsigned short hh[4], ll[4];
    #pragma unroll
    for (int j = 0; j < 4; ++j) {
        unsigned short h = f2bf(c[j]);
        float hf = __uint_as_float((unsigned)h << 16);
        hh[j] = h;
        ll[j] = f2bf(c[j] - hf);
    }
    *(ushort4*)(hi + i) = make_ushort4(hh[0], hh[1], hh[2], hh[3]);
    *(ushort4*)(lo + i) = make_ushort4(ll[0], ll[1], ll[2], ll[3]);
}

// W1 [n][h][u] fp32 -> BT_hi/lo [n][u][h] bf16 (transposed, K contiguous)
__global__ void convert_B(const float* __restrict__ W1,
                          unsigned short* __restrict__ bhi,
                          unsigned short* __restrict__ blo) {
    __shared__ float t[64][65];
    int n = blockIdx.x, h0 = blockIdx.y * 64, u0 = blockIdx.z * 64;
    int tid = threadIdx.x;
    int ul = tid & 63;
    #pragma unroll
    for (int i = 0; i < 16; ++i) {
        int hl = i * 4 + (tid >> 6);
        t[hl][ul] = W1[((size_t)n * H_ + h0 + hl) * U_ + u0 + ul];
    }
    __syncthreads();
    #pragma unroll
    for (int i = 0; i < 16; ++i) {
        int ulw = i * 4 + (tid >> 6);
        int hlw = tid & 63;
        float f = t[hlw][ulw];
        unsigned short h = f2bf(f);
        float hf = __uint_as_float((unsigned)h << 16);
        size_t o = ((size_t)n * U_ + u0 + ulw) * H_ + h0 + hlw;
        bhi[o] = h;
        blo[o] = f2bf(f - hf);
    }
}

// qb[n,b,u] = sum_h query[b,h]*W2[n,h,u] + b1[n,u] + b2[n,u]   (exact fp32)
__global__ void qb_kernel(const float* __restrict__ query,
                          const float* __restrict__ W2,
                          const float* __restrict__ b1,
                          const float* __restrict__ b2,
                          float* __restrict__ qb) {
    int n = blockIdx.x >> 4;
    int b = blockIdx.x & 15;
    __shared__ float q[H_];
    int tid = threadIdx.x;
    q[tid]       = query[b * H_ + tid];
    q[tid + 512] = query[b * H_ + tid + 512];
    __syncthreads();
    const float* w2 = W2 + (size_t)n * H_ * U_ + tid;
    float acc = 0.f;
    #pragma unroll 4
    for (int h = 0; h < H_; ++h) acc += q[h] * w2[(size_t)h * U_];
    acc += b1[n * U_ + tid] + b2[n * U_ + tid];
    qb[(n * B_ + b) * U_ + tid] = acc;
}

// ---------------- main GEMM: A via 4-slot LDS ring; B global->reg, chunk-prefetched ----------------
// Virtual K'=3072: seg0 Ahi*Bhi, seg1 Ahi*Blo, seg2 Alo*Bhi (96 K-tiles of 32).
// BM=BN=256, 8 waves (2x4). Chunk = 2 K-tiles; B chunk double-buffered (issued 1 chunk = 4 phases ahead).
#define NT 96
#define SWZ(d) ((d) ^ ((((d) >> 7) & 3) << 4))
#define ASRC(tt) (((tt) < 64) ? Ahi : Alo)
#define BSRC(tt) ((((tt) >> 5) == 1) ? Blo : Bhi)
#define K0(tt) (((tt) & 31) * 32)

#define STAGE_A(tt, j) gl16(ASRC(tt) + (size_t)(rowBase + (j)*128 + rT) * 1024 + K0(tt) + cT, \
                            lds + ((tt)&3)*8192 + (j)*4096 + tid*8)

#define LOADB_CH(dst, c_) do {                                           \
    const int t0_ = 2*(c_);                                              \
    const unsigned short* b0_ = BSRC(t0_) + bOff + K0(t0_);              \
    const unsigned short* b1_ = BSRC(t0_+1) + bOff + K0(t0_+1);          \
    dst[0] = *(const s16x8*)(b0_);                                       \
    dst[1] = *(const s16x8*)(b0_ + 16384);                               \
    dst[2] = *(const s16x8*)(b0_ + 32768);                               \
    dst[3] = *(const s16x8*)(b0_ + 49152);                               \
    dst[4] = *(const s16x8*)(b1_);                                       \
    dst[5] = *(const s16x8*)(b1_ + 16384);                               \
    dst[6] = *(const s16x8*)(b1_ + 32768);                               \
    dst[7] = *(const s16x8*)(b1_ + 49152);                               \
  } while (0)

#define MFMA_Q(MH, BB, BO) do {                                          \
    _Pragma("unroll") for (int m = 0; m < 4; ++m)                        \
      _Pragma("unroll") for (int n = 0; n < 4; ++n)                      \
        acc[(MH)*4 + m][n] = __builtin_amdgcn_mfma_f32_16x16x32_bf16(    \
            af_[m], BB[(BO) + n], acc[(MH)*4 + m][n], 0, 0, 0);          \
  } while (0)

#define RD_A(SL, MH) do {                                                \
    _Pragma("unroll") for (int m = 0; m < 4; ++m)                        \
        af_[m] = *(const s16x8*)((SL) + offA[(MH)*4 + m]);               \
  } while (0)

#define VMW(c_) do {                                                     \
    if ((c_) < 46) asm volatile("s_waitcnt vmcnt(12)" ::: "memory");     \
    else           asm volatile("s_waitcnt vmcnt(0)" ::: "memory");      \
  } while (0)

#define CHUNK(c_, BC, BN) do {                                           \
    if ((c_) + 1 < 48) LOADB_CH(BN, (c_) + 1);                           \
    const int te_ = 2*(c_), to_ = te_ + 1;                               \
    const char* se_ = (const char*)lds + (te_ & 3) * 16384;              \
    const char* so_ = (const char*)lds + (to_ & 3) * 16384;              \
    s16x8 af_[4];                                                        \
    /* ph0: A(te) m0-3 x BC[0..3] */                                     \
    RD_A(se_, 0);                                                        \
    if (te_ + 3 < NT) STAGE_A(te_ + 3, 0);                               \
    __builtin_amdgcn_s_barrier();                                        \
    __builtin_amdgcn_s_setprio(1);                                       \
    MFMA_Q(0, BC, 0);                                                    \
    __builtin_amdgcn_s_setprio(0);                                       \
    __builtin_amdgcn_s_barrier();                                        \
    /* ph1: A(te) m4-7 x BC[0..3] */                                     \
    RD_A(se_, 1);                                                        \
    if (te_ + 3 < NT) STAGE_A(te_ + 3, 1);                               \
    __builtin_amdgcn_s_barrier();                                        \
    __builtin_amdgcn_s_setprio(1);                                       \
    MFMA_Q(1, BC, 0);                                                    \
    __builtin_amdgcn_s_setprio(0);                                       \
    VMW(c_);                                                             \
    __builtin_amdgcn_s_barrier();                                        \
    /* ph2: A(to) m0-3 x BC[4..7] */                                     \
    RD_A(so_, 0);                                                        \
    if (to_ + 3 < NT) STAGE_A(to_ + 3, 0);                               \
    __builtin_amdgcn_s_barrier();                                        \
    __builtin_amdgcn_s_setprio(1);                                       \
    MFMA_Q(0, BC, 4);                                                    \
    __builtin_amdgcn_s_setprio(0);                                       \
    __builtin_amdgcn_s_barrier();                                        \
    /* ph3: A(to) m4-7 x BC[4..7] */                                     \
    RD_A(so_, 1);                                                        \
    if (to_ + 3 < NT) STAGE_A(to_ + 3, 1);                               \
    __builtin_amdgcn_s_barrier();                                        \
    __builtin_amdgcn_s_setprio(1);                                       \
    MFMA_Q(1, BC, 4);                                                    \
    __builtin_amdgcn_s_setprio(0);                                       \
    VMW(c_);                                                             \
    __builtin_amdgcn_s_barrier();                                        \
  } while (0)

__global__ __launch_bounds__(512, 1) void gemm8(
        const unsigned short* __restrict__ Ahi, const unsigned short* __restrict__ Alo,
        const unsigned short* __restrict__ Bhi, const unsigned short* __restrict__ Blo,
        const float* __restrict__ qb, const float* __restrict__ Vw,
        const float* __restrict__ Ww, float* __restrict__ partial) {
    __shared__ unsigned short lds[32768];   // 64 KB: 4 A-slots x 16 KB
    const int tid = threadIdx.x;
    const int lane = tid & 63;
    const int wid = tid >> 6;
    const int wm = wid >> 2, wn = wid & 3;   // 2 x 4 wave grid
    int bid = blockIdx.x;
    int swz = (bid & 7) * 256 + (bid >> 3);  // XCD swizzle (2048 % 8 == 0)
    int mIdx = swz & 127, nIdx = swz >> 7;
    int rowBase = mIdx * 256, colBase = nIdx * 256;

    // A staging decode: linear LDS dst -> swizzled global src
    int d0 = tid * 16;
    int d0s = SWZ(d0);
    int rT = d0s >> 6;          // row 0..127 within 128-row chunk
    int cT = (d0s & 63) >> 1;   // elem col (multiple of 8)

    // A fragment ds_read byte offsets (swizzled, slot-relative)
    const int l15 = lane & 15, l4 = lane >> 4;
    int offA[8];
    #pragma unroll
    for (int m = 0; m < 8; ++m) {
        int d = (wm * 128 + m * 16 + l15) * 64 + l4 * 16;
        offA[m] = SWZ(d);
    }
    // B per-lane global element offset (frag: row = col index, k = l4*8)
    const size_t bOff = ((size_t)(colBase + wn * 64 + l15)) * 1024 + l4 * 8;

    f32x4 acc[8][4];
    #pragma unroll
    for (int m = 0; m < 8; ++m)
        #pragma unroll
        for (int n = 0; n < 4; ++n) acc[m][n] = (f32x4){0.f, 0.f, 0.f, 0.f};

    s16x8 bX[8], bY[8];
    // prologue: B chunk0; stage A(0..2); A(0)+B(0) resident
    LOADB_CH(bX, 0);
    STAGE_A(0, 0); STAGE_A(0, 1);
    STAGE_A(1, 0); STAGE_A(1, 1);
    STAGE_A(2, 0); STAGE_A(2, 1);
    asm volatile("s_waitcnt vmcnt(4)" ::: "memory");
    __builtin_amdgcn_s_barrier();

    #pragma unroll 1
    for (int c = 0; c < 48; c += 2) {
        CHUNK(c, bX, bY);
        CHUNK(c + 1, bY, bX);
    }

    // epilogue: tanh + Vw*Ww row-reduce, cross-wave LDS reduce
    __syncthreads();
    int hd = colBase >> 9;
    int b = rowBase >> 11;
    float wwn = Ww[hd];
    float qv[4], vw[4];
    #pragma unroll
    for (int n = 0; n < 4; ++n) {
        int u = (colBase & 511) + wn * 64 + n * 16 + l15;
        qv[n] = qb[((size_t)hd * B_ + b) * U_ + u];
        vw[n] = Vw[hd * U_ + u] * wwn;
    }
    float* red = (float*)lds;   // [4 wn][256 rows]
    #pragma unroll
    for (int m = 0; m < 8; ++m)
        #pragma unroll
        for (int r = 0; r < 4; ++r) {
            float p = 0.f;
            #pragma unroll
            for (int n = 0; n < 4; ++n)
                p += vw[n] * fast_tanh(acc[m][n][r] + qv[n]);
            p += __shfl_xor(p, 1);
            p += __shfl_xor(p, 2);
            p += __shfl_xor(p, 4);
            p += __shfl_xor(p, 8);
            if (l15 == 0)
                red[wn * 256 + wm * 128 + m * 16 + l4 * 4 + r] = p;
        }
    __syncthreads();
    if (tid < 256) {
        float s = red[tid] + red[256 + tid] + red[512 + tid] + red[768 + tid];
        partial[(size_t)nIdx * M_ + rowBase + tid] = s;
    }
}

// ---------------- fallback fp32 GEMM (if ws too small) ----------------
__global__ __launch_bounds__(256, 2) void gemm_score(
        const float* __restrict__ values,
        const float* __restrict__ W1,
        const float* __restrict__ qb,
        const float* __restrict__ Vw,
        const float* __restrict__ Ww,
        float* __restrict__ partial) {
    __shared__ float As[16][128 + 4];
    __shared__ float Bs[16][128 + 4];
    int tid = threadIdx.x;
    int tx = tid & 15, ty = tid >> 4;
    int rowBase = blockIdx.x * 128;
    int colBase = blockIdx.y * 128;
    int n = colBase >> 9;
    int u0 = colBase & 511;
    int b = rowBase >> 11;
    float acc[8][8];
    #pragma unroll
    for (int i = 0; i < 8; ++i)
        #pragma unroll
        for (int j = 0; j < 8; ++j) acc[i][j] = 0.f;
    const float* Ag = values + (size_t)rowBase * H_;
    const float* Bg = W1 + (size_t)n * H_ * U_ + u0;
    for (int k0 = 0; k0 < H_; k0 += 16) {
        #pragma unroll
        for (int r = 0; r < 2; ++r) {
            int idx = tid + r * 256;
            int arow = idx >> 2, aqc = idx & 3;
            float4 v = *(const float4*)(Ag + (size_t)arow * H_ + k0 + aqc * 4);
            As[aqc * 4 + 0][arow] = v.x;
            As[aqc * 4 + 1][arow] = v.y;
            As[aqc * 4 + 2][arow] = v.z;
            As[aqc * 4 + 3][arow] = v.w;
        }
        #pragma unroll
        for (int r = 0; r < 2; ++r) {
            int idx = tid + r * 256;
            int bk = idx >> 5, bqc = idx & 31;
            float4 v = *(const float4*)(Bg + (size_t)(k0 + bk) * U_ + bqc * 4);
            *(float4*)&Bs[bk][bqc * 4] = v;
        }
        __syncthreads();
        #pragma unroll
        for (int k = 0; k < 16; ++k) {
            float4 a0 = *(const float4*)&As[k][ty * 8];
            float4 a1 = *(const float4*)&As[k][ty * 8 + 4];
            float4 b0 = *(const float4*)&Bs[k][tx * 8];
            float4 b1v = *(const float4*)&Bs[k][tx * 8 + 4];
            float av[8] = {a0.x, a0.y, a0.z, a0.w, a1.x, a1.y, a1.z, a1.w};
            float bv[8] = {b0.x, b0.y, b0.z, b0.w, b1v.x, b1v.y, b1v.z, b1v.w};
            #pragma unroll
            for (int i = 0; i < 8; ++i)
                #pragma unroll
                for (int j = 0; j < 8; ++j)
                    acc[i][j] = fmaf(av[i], bv[j], acc[i][j]);
        }
        __syncthreads();
    }
    float qbv[8], vwv[8];
    #pragma unroll
    for (int j = 0; j < 8; ++j) {
        int u = u0 + tx * 8 + j;
        qbv[j] = qb[(n * B_ + b) * U_ + u];
        vwv[j] = Vw[n * U_ + u];
    }
    float wwn = Ww[n];
    #pragma unroll
    for (int i = 0; i < 8; ++i) {
        float p = 0.f;
        #pragma unroll
        for (int j = 0; j < 8; ++j)
            p += vwv[j] * fast_tanh(acc[i][j] + qbv[j]);
        p += __shfl_xor(p, 1);
        p += __shfl_xor(p, 2);
        p += __shfl_xor(p, 4);
        p += __shfl_xor(p, 8);
        if (tx == 0)
            partial[(size_t)blockIdx.y * M_ + rowBase + ty * 8 + i] = wwn * p;
    }
}

// ---------------- tail kernels ----------------
__global__ void reduce_score(const float* __restrict__ partial,
                             float* __restrict__ score, int nparts) {
    int row = blockIdx.x * blockDim.x + threadIdx.x;
    float s = 0.f;
    for (int ct = 0; ct < nparts; ++ct) s += partial[(size_t)ct * M_ + row];
    score[row] = s;
}

__global__ __launch_bounds__(1024) void topk_kernel(
        const float* __restrict__ score,
        const float* __restrict__ Vb,
        const float* __restrict__ Ww,
        const float* __restrict__ Wb,
        float* __restrict__ out_masked,
        float* __restrict__ w_un) {
    __shared__ float sc[S_];
    __shared__ float srt[S_];
    __shared__ int cnt_gt;
    int b = blockIdx.x;
    int tid = threadIdx.x;
    float cst = Wb[0];
    #pragma unroll
    for (int n2 = 0; n2 < NH; ++n2) cst += Ww[n2] * Vb[n2];
    for (int s = tid; s < S_; s += 1024) {
        float v = score[b * S_ + s] + cst;
        sc[s] = v; srt[s] = v;
    }
    if (tid == 0) cnt_gt = 0;
    __syncthreads();
    for (int k = 2; k <= S_; k <<= 1) {
        for (int j = k >> 1; j >= 1; j >>= 1) {
            int i = ((tid & ~(j - 1)) << 1) | (tid & (j - 1));
            int p = i | j;
            float a = srt[i], c2 = srt[p];
            if (((i & k) == 0) ? (a > c2) : (a < c2)) { srt[i] = c2; srt[p] = a; }
            __syncthreads();
        }
    }
    float T = srt[S_ - TOPK];
    int c = 0;
    for (int s = tid; s < S_; s += 1024) c += (sc[s] > T);
    atomicAdd(&cnt_gt, c);
    __syncthreads();
    int need_eq = TOPK - cnt_gt;
    for (int s = tid; s < S_; s += 1024) {
        float v = sc[s];
        bool sel = (v > T);
        if (v == T) {
            int rank = 0;
            for (int t2 = 0; t2 < s; ++t2) rank += (sc[t2] == T);
            sel = (rank < need_eq);
        }
        float m = sel ? v : 0.f;
        out_masked[b * S_ + s] = m;
        w_un[b * S_ + s] = 1.f / (1.f + __expf(-m));
    }
}

__global__ void norm_w(const float* __restrict__ w_un, float* __restrict__ out_w) {
    int s = blockIdx.x * blockDim.x + threadIdx.x;
    float d = 0.f;
    #pragma unroll
    for (int b = 0; b < B_; ++b) d += w_un[b * S_ + s];
    float inv = 1.f / d;
    #pragma unroll
    for (int b = 0; b < B_; ++b) out_w[b * S_ + s] = w_un[b * S_ + s] * inv;
}

// context partials; values as bf16 (Ahi) halves read traffic
__global__ void ctx_partial_bf(const unsigned short* __restrict__ vbf,
                               const float* __restrict__ w,
                               float* __restrict__ pctx) {
    int bb = blockIdx.x;
    int h = blockIdx.y * 256 + threadIdx.x;
    int s0 = blockIdx.z * 256;
    __shared__ float wrow[256];
    wrow[threadIdx.x] = w[bb * S_ + s0 + threadIdx.x];
    __syncthreads();
    const unsigned short* vp = vbf + (size_t)(bb * S_ + s0) * H_ + h;
    float acc = 0.f;
    #pragma unroll 4
    for (int s = 0; s < 256; ++s) {
        float v = __uint_as_float((unsigned)vp[(size_t)s * H_] << 16);
        acc += wrow[s] * v;
    }
    pctx[((size_t)blockIdx.z * B_ + bb) * H_ + h] = acc;
}

__global__ void ctx_partial_f32(const float* __restrict__ values,
                                const float* __restrict__ w,
                                float* __restrict__ pctx) {
    int bb = blockIdx.x;
    int h = blockIdx.y * 256 + threadIdx.x;
    int s0 = blockIdx.z * 256;
    __shared__ float wrow[256];
    wrow[threadIdx.x] = w[bb * S_ + s0 + threadIdx.x];
    __syncthreads();
    const float* vp = values + (size_t)(bb * S_ + s0) * H_ + h;
    float acc = 0.f;
    #pragma unroll 4
    for (int s = 0; s < 256; ++s) acc += wrow[s] * vp[(size_t)s * H_];
    pctx[((size_t)blockIdx.z * B_ + bb) * H_ + h] = acc;
}

__global__ void ctx_reduce(const float* __restrict__ pctx,
                           float* __restrict__ out_ctx) {
    int i = blockIdx.x * blockDim.x + threadIdx.x;
    float s = 0.f;
    #pragma unroll
    for (int z = 0; z < 8; ++z) s += pctx[(size_t)z * B_ * H_ + i];
    out_ctx[i] = s;
}

extern "C" void kernel_launch(void* const* d_in, const int* in_sizes, int n_in,
                              void* d_out, int out_size, void* d_ws, size_t ws_size,
                              hipStream_t stream) {
    const float* query = (const float*)d_in[0];
    const float* values = (const float*)d_in[1];
    const float* W1 = (const float*)d_in[2];
    const float* b1 = (const float*)d_in[3];
    const float* W2 = (const float*)d_in[4];
    const float* b2 = (const float*)d_in[5];
    const float* Vw = (const float*)d_in[6];
    const float* Vb = (const float*)d_in[7];
    const float* Ww = (const float*)d_in[8];
    const float* Wb = (const float*)d_in[9];

    float* ws = (float*)d_ws;
    float* qb      = ws;                     // 65536
    float* partial = qb + 65536;             // 32*32768
    float* score   = partial + 1048576;      // 32768
    float* w_un    = score + 32768;          // 32768
    float* pctx    = w_un + 32768;           // 131072
    unsigned short* Ahi = (unsigned short*)(pctx + 131072);
    unsigned short* Alo = Ahi + (size_t)M_ * H_;
    unsigned short* Bhi = Alo + (size_t)M_ * H_;
    unsigned short* Blo = Bhi + (size_t)NC * H_;
    size_t needed = (size_t)((char*)(Blo + (size_t)NC * H_) - (char*)d_ws);

    float* out_ctx    = (float*)d_out;       // 16384
    float* out_w      = out_ctx + 16384;     // 32768
    float* out_masked = out_w + 32768;       // 32768

    qb_kernel<<<dim3(NH * B_), 512, 0, stream>>>(query, W2, b1, b2, qb);
    if (ws_size >= needed) {
        convert_A<<<dim3(32768), 256, 0, stream>>>(values, Ahi, Alo);
        convert_B<<<dim3(NH, 16, 8), 256, 0, stream>>>(W1, Bhi, Blo);
        gemm8<<<dim3(2048), 512, 0, stream>>>(Ahi, Alo, Bhi, Blo, qb, Vw, Ww, partial);
        reduce_score<<<128, 256, 0, stream>>>(partial, score, 16);
        topk_kernel<<<16, 1024, 0, stream>>>(score, Vb, Ww, Wb, out_masked, w_un);
        norm_w<<<8, 256, 0, stream>>>(w_un, out_w);
        ctx_partial_bf<<<dim3(16, 4, 8), 256, 0, stream>>>(Ahi, out_w, pctx);
    } else {
        gemm_score<<<dim3(256, 32), 256, 0, stream>>>(values, W1, qb, Vw, Ww, partial);
        reduce_score<<<128, 256, 0, stream>>>(partial, score, 32);
        topk_kernel<<<16, 1024, 0, stream>>>(score, Vb, Ww, Wb, out_masked, w_un);
        norm_w<<<8, 256, 0, stream>>>(w_un, out_w);
        ctx_partial_f32<<<dim3(16, 4, 8), 256, 0, stream>>>(values, out_w, pctx);
    }
    ctx_reduce<<<64, 256, 0, stream>>>(pctx, out_ctx);
}

// Round 6
// 736.796 us; speedup vs baseline: 2.7614x; 2.7614x over previous
//
#include <hip/hip_runtime.h>
#include <hip/hip_bf16.h>

#define B_ 16
#define S_ 2048
#define H_ 1024
#define U_ 512
#define NH 8
#define TOPK 100

#define M_ (B_*S_)      // 32768 rows (b,s)
#define NC (NH*U_)      // 4096 cols (n,u)

typedef int i32x4 __attribute__((ext_vector_type(4)));

__device__ __forceinline__ float fast_tanh(float x) {
    float e = __expf(2.f * x);
    return (e - 1.f) / (e + 1.f);
}

__device__ __forceinline__ void gl16i(const signed char* g, signed char* l) {
    __builtin_amdgcn_global_load_lds(
        (const __attribute__((address_space(1))) void*)g,
        (__attribute__((address_space(3))) void*)l, 16, 0, 0);
}

// ---------------- prep: int8 two-level quantization ----------------
// values: one wave per row; x ~= sa*(h + l/128), h,l in [-127,127]/[-64,64]
__global__ void cvtA(const float* __restrict__ v,
                     signed char* __restrict__ h8,
                     signed char* __restrict__ l8,
                     float* __restrict__ sa) {
    int row = blockIdx.x * 4 + (threadIdx.x >> 6);
    int l = threadIdx.x & 63;
    const float4* r4 = (const float4*)(v + (size_t)row * 1024);
    float4 x[4];
    float mx = 0.f;
    #pragma unroll
    for (int c = 0; c < 4; ++c) {
        x[c] = r4[l * 4 + c];
        mx = fmaxf(mx, fmaxf(fmaxf(fabsf(x[c].x), fabsf(x[c].y)),
                             fmaxf(fabsf(x[c].z), fabsf(x[c].w))));
    }
    #pragma unroll
    for (int d = 1; d < 64; d <<= 1) mx = fmaxf(mx, __shfl_xor(mx, d));
    float inv = 127.f / mx;
    int wh[4], wl[4];
    #pragma unroll
    for (int c = 0; c < 4; ++c) {
        float xs[4] = {x[c].x, x[c].y, x[c].z, x[c].w};
        unsigned ph = 0, pl = 0;
        #pragma unroll
        for (int j = 0; j < 4; ++j) {
            float y = xs[j] * inv;
            float hf = rintf(y);
            float lf = rintf((y - hf) * 128.f);
            ph |= ((unsigned)((int)hf) & 0xffu) << (8 * j);
            pl |= ((unsigned)((int)lf) & 0xffu) << (8 * j);
        }
        wh[c] = (int)ph; wl[c] = (int)pl;
    }
    *(int4*)(h8 + (size_t)row * 1024 + l * 16) = make_int4(wh[0], wh[1], wh[2], wh[3]);
    *(int4*)(l8 + (size_t)row * 1024 + l * 16) = make_int4(wl[0], wl[1], wl[2], wl[3]);
    if (l == 0) sa[row] = mx / 127.f;
}

// per-column (n,u) scales of W1: sbq = colmax/127/128 (epilogue), sbinv = 127/colmax
__global__ void cvtBs(const float* __restrict__ W1,
                      float* __restrict__ sbq, float* __restrict__ sbinv) {
    int col = blockIdx.x;            // n*512+u
    int n = col >> 9, u = col & 511;
    int l = threadIdx.x;             // 64
    const float* p = W1 + (size_t)n * H_ * U_ + u;
    float mx = 0.f;
    for (int h = l; h < H_; h += 64) mx = fmaxf(mx, fabsf(p[(size_t)h * U_]));
    #pragma unroll
    for (int d = 1; d < 64; d <<= 1) mx = fmaxf(mx, __shfl_xor(mx, d));
    if (l == 0) { sbq[col] = mx / (127.f * 128.f); sbinv[col] = 127.f / mx; }
}

// W1 [n][h][u] -> BT h/l int8 [n][u][h] (transposed, K=h contiguous)
__global__ void cvtB8(const float* __restrict__ W1,
                      const float* __restrict__ sbinv,
                      signed char* __restrict__ bh, signed char* __restrict__ bl) {
    __shared__ float t[64][65];
    int n = blockIdx.x, h0 = blockIdx.y * 64, u0 = blockIdx.z * 64;
    int tid = threadIdx.x;
    int ul = tid & 63;
    #pragma unroll
    for (int i = 0; i < 16; ++i) {
        int hl = i * 4 + (tid >> 6);
        t[hl][ul] = W1[((size_t)n * H_ + h0 + hl) * U_ + u0 + ul];
    }
    __syncthreads();
    #pragma unroll
    for (int i = 0; i < 16; ++i) {
        int ulw = i * 4 + (tid >> 6);
        int hlw = tid & 63;
        float q = t[hlw][ulw] * sbinv[n * 512 + u0 + ulw];
        float hf = rintf(q);
        float lf = rintf((q - hf) * 128.f);
        size_t o = ((size_t)(n * 512 + u0 + ulw)) * 1024 + h0 + hlw;
        bh[o] = (signed char)(int)hf;
        bl[o] = (signed char)(int)lf;
    }
}

// qb[n,b,u] = sum_h query[b,h]*W2[n,h,u] + b1[n,u] + b2[n,u]   (exact fp32)
__global__ void qb_kernel(const float* __restrict__ query,
                          const float* __restrict__ W2,
                          const float* __restrict__ b1,
                          const float* __restrict__ b2,
                          float* __restrict__ qb) {
    int n = blockIdx.x >> 4;
    int b = blockIdx.x & 15;
    __shared__ float q[H_];
    int tid = threadIdx.x;
    q[tid]       = query[b * H_ + tid];
    q[tid + 512] = query[b * H_ + tid + 512];
    __syncthreads();
    const float* w2 = W2 + (size_t)n * H_ * U_ + tid;
    float acc = 0.f;
    #pragma unroll 4
    for (int h = 0; h < H_; ++h) acc += q[h] * w2[(size_t)h * U_];
    acc += b1[n * U_ + tid] + b2[n * U_ + tid];
    qb[(n * B_ + b) * U_ + tid] = acc;
}

// ---------------- main GEMM: int8 3-pass, single i32 accumulator ----------------
// K'=3072 virtual (48 tiles of K=64): t<16 HH, 16-31 H*Blo, 32-47 Alo*Bh.
// acc <<= 7 between segment 1 and 2. BM=BN=256, 8 waves, 4-slot LDS ring (32KB/tile).
#define NT 48
#define SWZ(d) ((d) ^ ((((d) >> 7) & 3) << 4))
#define ASRC(tt) (((tt) < 32) ? Ah8 : Al8)
#define BSRC(tt) ((((tt) >> 4) == 1) ? Bl8 : Bh8)
#define K0B(tt) (((tt) & 15) * 64)
#define STAGE_A(tt, j) gl16i(ASRC(tt) + (size_t)(rowBase + (j)*128 + rT) * 1024 + K0B(tt) + cTb, \
                             lds + ((tt)&3)*32768 + (j)*8192 + tid*16)
#define STAGE_B(tt, j) gl16i(BSRC(tt) + (size_t)(colBase + (j)*128 + rT) * 1024 + K0B(tt) + cTb, \
                             lds + ((tt)&3)*32768 + 16384 + (j)*8192 + tid*16)

__global__ __launch_bounds__(512, 1) void gemm8i(
        const signed char* __restrict__ Ah8, const signed char* __restrict__ Al8,
        const signed char* __restrict__ Bh8, const signed char* __restrict__ Bl8,
        const float* __restrict__ sa, const float* __restrict__ sbq,
        const float* __restrict__ qb, const float* __restrict__ Vw,
        const float* __restrict__ Ww, float* __restrict__ partial) {
    __shared__ signed char lds[131072];   // 4 slots x (A 16KB | B 16KB)
    const int tid = threadIdx.x;
    const int lane = tid & 63;
    const int wid = tid >> 6;
    const int wm = wid >> 2, wn = wid & 3;   // 2 x 4 wave grid
    int bid = blockIdx.x;
    int swz = (bid & 7) * 256 + (bid >> 3);  // XCD swizzle (2048 % 8 == 0)
    int mIdx = swz & 127, nIdx = swz >> 7;
    int rowBase = mIdx * 256, colBase = nIdx * 256;

    // staging decode: linear LDS dst -> swizzled global src (8KB chunk)
    int d0 = tid * 16;
    int d0s = SWZ(d0);
    int rT  = d0s >> 6;       // row 0..127 within chunk
    int cTb = d0s & 63;       // byte col within 64B row

    // fragment ds_read byte offsets (swizzled, slot-relative)
    const int l15 = lane & 15, l4 = lane >> 4;
    int offA[8], offB[4];
    #pragma unroll
    for (int m = 0; m < 8; ++m)
        offA[m] = SWZ((wm * 128 + m * 16 + l15) * 64 + l4 * 16);
    #pragma unroll
    for (int n = 0; n < 4; ++n)
        offB[n] = 16384 + SWZ((wn * 64 + n * 16 + l15) * 64 + l4 * 16);

    i32x4 acc[8][4];
    #pragma unroll
    for (int m = 0; m < 8; ++m)
        #pragma unroll
        for (int n = 0; n < 4; ++n) acc[m][n] = (i32x4){0, 0, 0, 0};

    // prologue: stage tiles 0..2 (12 loads)
    #pragma unroll
    for (int tt = 0; tt < 3; ++tt) {
        STAGE_A(tt, 0); STAGE_A(tt, 1);
        STAGE_B(tt, 0); STAGE_B(tt, 1);
    }
    asm volatile("s_waitcnt vmcnt(8)" ::: "memory");   // tile 0 resident
    __builtin_amdgcn_s_barrier();

    #pragma unroll 1
    for (int t = 0; t < NT; ++t) {
        if (t == 16) {   // HH pass done over full K: scale by 128 before HL/LH
            #pragma unroll
            for (int m = 0; m < 8; ++m)
                #pragma unroll
                for (int n = 0; n < 4; ++n) acc[m][n] = acc[m][n] << 7;
        }
        const signed char* slot = lds + (t & 3) * 32768;
        i32x4 bf[4], af[4];
        // ---- phase 0: B frags + A m0-3, stage A(t+3), MFMA quadrant 0 ----
        #pragma unroll
        for (int n = 0; n < 4; ++n) bf[n] = *(const i32x4*)(slot + offB[n]);
        #pragma unroll
        for (int m = 0; m < 4; ++m) af[m] = *(const i32x4*)(slot + offA[m]);
        if (t <= NT - 4) { STAGE_A(t + 3, 0); STAGE_A(t + 3, 1); }
        __builtin_amdgcn_s_barrier();
        asm volatile("s_waitcnt lgkmcnt(0)" ::: "memory");
        __builtin_amdgcn_s_setprio(1);
        #pragma unroll
        for (int m = 0; m < 4; ++m)
            #pragma unroll
            for (int n = 0; n < 4; ++n)
                acc[m][n] = __builtin_amdgcn_mfma_i32_16x16x64_i8(af[m], bf[n], acc[m][n], 0, 0, 0);
        __builtin_amdgcn_s_setprio(0);
        __builtin_amdgcn_s_barrier();
        // ---- phase 1: A m4-7, stage B(t+3), MFMA quadrant 1, boundary vmcnt ----
        #pragma unroll
        for (int m = 0; m < 4; ++m) af[m] = *(const i32x4*)(slot + offA[4 + m]);
        if (t <= NT - 4) { STAGE_B(t + 3, 0); STAGE_B(t + 3, 1); }
        __builtin_amdgcn_s_barrier();
        asm volatile("s_waitcnt lgkmcnt(0)" ::: "memory");
        __builtin_amdgcn_s_setprio(1);
        #pragma unroll
        for (int m = 0; m < 4; ++m)
            #pragma unroll
            for (int n = 0; n < 4; ++n)
                acc[4 + m][n] = __builtin_amdgcn_mfma_i32_16x16x64_i8(af[m], bf[n], acc[4 + m][n], 0, 0, 0);
        __builtin_amdgcn_s_setprio(0);
        if (t < NT - 3)       asm volatile("s_waitcnt vmcnt(8)" ::: "memory");
        else if (t == NT - 3) asm volatile("s_waitcnt vmcnt(4)" ::: "memory");
        else if (t == NT - 2) asm volatile("s_waitcnt vmcnt(0)" ::: "memory");
        __builtin_amdgcn_s_barrier();
    }

    // epilogue: Cf = acc*sa*sbq; tanh + Vw*Ww row-reduce; cross-wave LDS reduce
    __syncthreads();
    int hd = colBase >> 9;
    int b = rowBase >> 11;
    float wwn = Ww[hd];
    float qv[4], vw[4], sbv[4];
    #pragma unroll
    for (int n = 0; n < 4; ++n) {
        int col = colBase + wn * 64 + n * 16 + l15;
        int u = col & 511;
        qv[n] = qb[((size_t)hd * B_ + b) * U_ + u];
        vw[n] = Vw[hd * U_ + u] * wwn;
        sbv[n] = sbq[col];
    }
    float* red = (float*)lds;   // [4 wn][256 rows]
    #pragma unroll
    for (int m = 0; m < 8; ++m) {
        float sav[4];
        #pragma unroll
        for (int r = 0; r < 4; ++r)
            sav[r] = sa[rowBase + wm * 128 + m * 16 + l4 * 4 + r];
        #pragma unroll
        for (int r = 0; r < 4; ++r) {
            float p = 0.f;
            #pragma unroll
            for (int n = 0; n < 4; ++n)
                p += vw[n] * fast_tanh((float)acc[m][n][r] * sav[r] * sbv[n] + qv[n]);
            p += __shfl_xor(p, 1);
            p += __shfl_xor(p, 2);
            p += __shfl_xor(p, 4);
            p += __shfl_xor(p, 8);
            if (l15 == 0)
                red[wn * 256 + wm * 128 + m * 16 + l4 * 4 + r] = p;
        }
    }
    __syncthreads();
    if (tid < 256) {
        float s = red[tid] + red[256 + tid] + red[512 + tid] + red[768 + tid];
        partial[(size_t)nIdx * M_ + rowBase + tid] = s;
    }
}

// ---------------- fallback fp32 GEMM (if ws too small) ----------------
__global__ __launch_bounds__(256, 2) void gemm_score(
        const float* __restrict__ values,
        const float* __restrict__ W1,
        const float* __restrict__ qb,
        const float* __restrict__ Vw,
        const float* __restrict__ Ww,
        float* __restrict__ partial) {
    __shared__ float As[16][128 + 4];
    __shared__ float Bs[16][128 + 4];
    int tid = threadIdx.x;
    int tx = tid & 15, ty = tid >> 4;
    int rowBase = blockIdx.x * 128;
    int colBase = blockIdx.y * 128;
    int n = colBase >> 9;
    int u0 = colBase & 511;
    int b = rowBase >> 11;
    float acc[8][8];
    #pragma unroll
    for (int i = 0; i < 8; ++i)
        #pragma unroll
        for (int j = 0; j < 8; ++j) acc[i][j] = 0.f;
    const float* Ag = values + (size_t)rowBase * H_;
    const float* Bg = W1 + (size_t)n * H_ * U_ + u0;
    for (int k0 = 0; k0 < H_; k0 += 16) {
        #pragma unroll
        for (int r = 0; r < 2; ++r) {
            int idx = tid + r * 256;
            int arow = idx >> 2, aqc = idx & 3;
            float4 v = *(const float4*)(Ag + (size_t)arow * H_ + k0 + aqc * 4);
            As[aqc * 4 + 0][arow] = v.x;
            As[aqc * 4 + 1][arow] = v.y;
            As[aqc * 4 + 2][arow] = v.z;
            As[aqc * 4 + 3][arow] = v.w;
        }
        #pragma unroll
        for (int r = 0; r < 2; ++r) {
            int idx = tid + r * 256;
            int bk = idx >> 5, bqc = idx & 31;
            float4 v = *(const float4*)(Bg + (size_t)(k0 + bk) * U_ + bqc * 4);
            *(float4*)&Bs[bk][bqc * 4] = v;
        }
        __syncthreads();
        #pragma unroll
        for (int k = 0; k < 16; ++k) {
            float4 a0 = *(const float4*)&As[k][ty * 8];
            float4 a1 = *(const float4*)&As[k][ty * 8 + 4];
            float4 b0 = *(const float4*)&Bs[k][tx * 8];
            float4 b1v = *(const float4*)&Bs[k][tx * 8 + 4];
            float av[8] = {a0.x, a0.y, a0.z, a0.w, a1.x, a1.y, a1.z, a1.w};
            float bv[8] = {b0.x, b0.y, b0.z, b0.w, b1v.x, b1v.y, b1v.z, b1v.w};
            #pragma unroll
            for (int i = 0; i < 8; ++i)
                #pragma unroll
                for (int j = 0; j < 8; ++j)
                    acc[i][j] = fmaf(av[i], bv[j], acc[i][j]);
        }
        __syncthreads();
    }
    float qbv[8], vwv[8];
    #pragma unroll
    for (int j = 0; j < 8; ++j) {
        int u = u0 + tx * 8 + j;
        qbv[j] = qb[(n * B_ + b) * U_ + u];
        vwv[j] = Vw[n * U_ + u];
    }
    float wwn = Ww[n];
    #pragma unroll
    for (int i = 0; i < 8; ++i) {
        float p = 0.f;
        #pragma unroll
        for (int j = 0; j < 8; ++j)
            p += vwv[j] * fast_tanh(acc[i][j] + qbv[j]);
        p += __shfl_xor(p, 1);
        p += __shfl_xor(p, 2);
        p += __shfl_xor(p, 4);
        p += __shfl_xor(p, 8);
        if (tx == 0)
            partial[(size_t)blockIdx.y * M_ + rowBase + ty * 8 + i] = wwn * p;
    }
}

// ---------------- tail kernels ----------------
__global__ void reduce_score(const float* __restrict__ partial,
                             float* __restrict__ score, int nparts) {
    int row = blockIdx.x * blockDim.x + threadIdx.x;
    float s = 0.f;
    for (int ct = 0; ct < nparts; ++ct) s += partial[(size_t)ct * M_ + row];
    score[row] = s;
}

__global__ __launch_bounds__(1024) void topk_kernel(
        const float* __restrict__ score,
        const float* __restrict__ Vb,
        const float* __restrict__ Ww,
        const float* __restrict__ Wb,
        float* __restrict__ out_masked,
        float* __restrict__ w_un) {
    __shared__ float sc[S_];
    __shared__ float srt[S_];
    __shared__ int cnt_gt;
    int b = blockIdx.x;
    int tid = threadIdx.x;
    float cst = Wb[0];
    #pragma unroll
    for (int n2 = 0; n2 < NH; ++n2) cst += Ww[n2] * Vb[n2];
    for (int s = tid; s < S_; s += 1024) {
        float v = score[b * S_ + s] + cst;
        sc[s] = v; srt[s] = v;
    }
    if (tid == 0) cnt_gt = 0;
    __syncthreads();
    for (int k = 2; k <= S_; k <<= 1) {
        for (int j = k >> 1; j >= 1; j >>= 1) {
            int i = ((tid & ~(j - 1)) << 1) | (tid & (j - 1));
            int p = i | j;
            float a = srt[i], c2 = srt[p];
            if (((i & k) == 0) ? (a > c2) : (a < c2)) { srt[i] = c2; srt[p] = a; }
            __syncthreads();
        }
    }
    float T = srt[S_ - TOPK];
    int c = 0;
    for (int s = tid; s < S_; s += 1024) c += (sc[s] > T);
    atomicAdd(&cnt_gt, c);
    __syncthreads();
    int need_eq = TOPK - cnt_gt;
    for (int s = tid; s < S_; s += 1024) {
        float v = sc[s];
        bool sel = (v > T);
        if (v == T) {
            int rank = 0;
            for (int t2 = 0; t2 < s; ++t2) rank += (sc[t2] == T);
            sel = (rank < need_eq);
        }
        float m = sel ? v : 0.f;
        out_masked[b * S_ + s] = m;
        w_un[b * S_ + s] = 1.f / (1.f + __expf(-m));
    }
}

__global__ void norm_w(const float* __restrict__ w_un, float* __restrict__ out_w) {
    int s = blockIdx.x * blockDim.x + threadIdx.x;
    float d = 0.f;
    #pragma unroll
    for (int b = 0; b < B_; ++b) d += w_un[b * S_ + s];
    float inv = 1.f / d;
    #pragma unroll
    for (int b = 0; b < B_; ++b) out_w[b * S_ + s] = w_un[b * S_ + s] * inv;
}

__global__ void ctx_partial_f32(const float* __restrict__ values,
                                const float* __restrict__ w,
                                float* __restrict__ pctx) {
    int bb = blockIdx.x;
    int h = blockIdx.y * 256 + threadIdx.x;
    int s0 = blockIdx.z * 256;
    __shared__ float wrow[256];
    wrow[threadIdx.x] = w[bb * S_ + s0 + threadIdx.x];
    __syncthreads();
    const float* vp = values + (size_t)(bb * S_ + s0) * H_ + h;
    float acc = 0.f;
    #pragma unroll 4
    for (int s = 0; s < 256; ++s) acc += wrow[s] * vp[(size_t)s * H_];
    pctx[((size_t)blockIdx.z * B_ + bb) * H_ + h] = acc;
}

__global__ void ctx_reduce(const float* __restrict__ pctx,
                           float* __restrict__ out_ctx) {
    int i = blockIdx.x * blockDim.x + threadIdx.x;
    float s = 0.f;
    #pragma unroll
    for (int z = 0; z < 8; ++z) s += pctx[(size_t)z * B_ * H_ + i];
    out_ctx[i] = s;
}

extern "C" void kernel_launch(void* const* d_in, const int* in_sizes, int n_in,
                              void* d_out, int out_size, void* d_ws, size_t ws_size,
                              hipStream_t stream) {
    const float* query = (const float*)d_in[0];
    const float* values = (const float*)d_in[1];
    const float* W1 = (const float*)d_in[2];
    const float* b1 = (const float*)d_in[3];
    const float* W2 = (const float*)d_in[4];
    const float* b2 = (const float*)d_in[5];
    const float* Vw = (const float*)d_in[6];
    const float* Vb = (const float*)d_in[7];
    const float* Ww = (const float*)d_in[8];
    const float* Wb = (const float*)d_in[9];

    float* ws = (float*)d_ws;
    float* qb      = ws;                     // 65536
    float* partial = qb + 65536;             // 1048576
    float* score   = partial + 1048576;      // 32768
    float* w_un    = score + 32768;          // 32768
    float* pctx    = w_un + 32768;           // 131072
    float* sa      = pctx + 131072;          // 32768
    float* sbq     = sa + 32768;             // 4096
    float* sbinv   = sbq + 4096;             // 4096
    signed char* Ah8 = (signed char*)(sbinv + 4096);   // 32 MB
    signed char* Al8 = Ah8 + (size_t)M_ * H_;          // 32 MB
    signed char* Bh8 = Al8 + (size_t)M_ * H_;          // 4 MB
    signed char* Bl8 = Bh8 + (size_t)NC * H_;          // 4 MB
    size_t needed = (size_t)((char*)(Bl8 + (size_t)NC * H_) - (char*)d_ws);

    float* out_ctx    = (float*)d_out;       // 16384
    float* out_w      = out_ctx + 16384;     // 32768
    float* out_masked = out_w + 32768;       // 32768

    qb_kernel<<<dim3(NH * B_), 512, 0, stream>>>(query, W2, b1, b2, qb);
    if (ws_size >= needed) {
        cvtA<<<dim3(8192), 256, 0, stream>>>(values, Ah8, Al8, sa);
        cvtBs<<<dim3(NC), 64, 0, stream>>>(W1, sbq, sbinv);
        cvtB8<<<dim3(NH, 16, 8), 256, 0, stream>>>(W1, sbinv, Bh8, Bl8);
        gemm8i<<<dim3(2048), 512, 0, stream>>>(Ah8, Al8, Bh8, Bl8, sa, sbq,
                                               qb, Vw, Ww, partial);
        reduce_score<<<128, 256, 0, stream>>>(partial, score, 16);
    } else {
        gemm_score<<<dim3(256, 32), 256, 0, stream>>>(values, W1, qb, Vw, Ww, partial);
        reduce_score<<<128, 256, 0, stream>>>(partial, score, 32);
    }
    topk_kernel<<<16, 1024, 0, stream>>>(score, Vb, Ww, Wb, out_masked, w_un);
    norm_w<<<8, 256, 0, stream>>>(w_un, out_w);
    ctx_partial_f32<<<dim3(16, 4, 8), 256, 0, stream>>>(values, out_w, pctx);
    ctx_reduce<<<64, 256, 0, stream>>>(pctx, out_ctx);
}

// Round 7
// 708.161 us; speedup vs baseline: 2.8731x; 1.0404x over previous
//
#include <hip/hip_runtime.h>
#include <hip/hip_bf16.h>

#define B_ 16
#define S_ 2048
#define H_ 1024
#define U_ 512
#define NH 8
#define TOPK 100

#define M_ (B_*S_)      // 32768 rows (b,s)
#define NC (NH*U_)      // 4096 cols (n,u)

typedef int i32x4 __attribute__((ext_vector_type(4)));

__device__ __forceinline__ float fast_tanh(float x) {
    float e = __expf(2.f * x);
    return (e - 1.f) / (e + 1.f);
}

__device__ __forceinline__ void gl16i(const signed char* g, signed char* l) {
    __builtin_amdgcn_global_load_lds(
        (const __attribute__((address_space(1))) void*)g,
        (__attribute__((address_space(3))) void*)l, 16, 0, 0);
}

// ---------------- prep: int8 two-level quantization ----------------
// values: one wave per row; x ~= sa*(h + l/128), h,l in [-127,127]/[-64,64]
__global__ void cvtA(const float* __restrict__ v,
                     signed char* __restrict__ h8,
                     signed char* __restrict__ l8,
                     float* __restrict__ sa) {
    int row = blockIdx.x * 4 + (threadIdx.x >> 6);
    int l = threadIdx.x & 63;
    const float4* r4 = (const float4*)(v + (size_t)row * 1024);
    float4 x[4];
    float mx = 0.f;
    #pragma unroll
    for (int c = 0; c < 4; ++c) {
        x[c] = r4[l * 4 + c];
        mx = fmaxf(mx, fmaxf(fmaxf(fabsf(x[c].x), fabsf(x[c].y)),
                             fmaxf(fabsf(x[c].z), fabsf(x[c].w))));
    }
    #pragma unroll
    for (int d = 1; d < 64; d <<= 1) mx = fmaxf(mx, __shfl_xor(mx, d));
    float inv = 127.f / mx;
    int wh[4], wl[4];
    #pragma unroll
    for (int c = 0; c < 4; ++c) {
        float xs[4] = {x[c].x, x[c].y, x[c].z, x[c].w};
        unsigned ph = 0, pl = 0;
        #pragma unroll
        for (int j = 0; j < 4; ++j) {
            float y = xs[j] * inv;
            float hf = rintf(y);
            float lf = rintf((y - hf) * 128.f);
            ph |= ((unsigned)((int)hf) & 0xffu) << (8 * j);
            pl |= ((unsigned)((int)lf) & 0xffu) << (8 * j);
        }
        wh[c] = (int)ph; wl[c] = (int)pl;
    }
    *(int4*)(h8 + (size_t)row * 1024 + l * 16) = make_int4(wh[0], wh[1], wh[2], wh[3]);
    *(int4*)(l8 + (size_t)row * 1024 + l * 16) = make_int4(wl[0], wl[1], wl[2], wl[3]);
    if (l == 0) sa[row] = mx / 127.f;
}

// ---- coalesced per-column max of |W1| via atomicMax on uint ----
__global__ void colmax_init(float* __restrict__ cm) {
    cm[blockIdx.x * 256 + threadIdx.x] = 0.f;
}
__global__ void colmax_kernel(const float* __restrict__ W1, float* __restrict__ cm) {
    int n = blockIdx.x, h0 = blockIdx.y * 64, u = threadIdx.x;  // 512 threads
    const float* p = W1 + ((size_t)n * H_ + h0) * U_ + u;
    float mx = 0.f;
    #pragma unroll 8
    for (int h = 0; h < 64; ++h) mx = fmaxf(mx, fabsf(p[(size_t)h * U_]));
    atomicMax((unsigned*)(cm + n * U_ + u), __float_as_uint(mx));
}
__global__ void colmax_fin(const float* __restrict__ cm,
                           float* __restrict__ sbq, float* __restrict__ sbinv) {
    int c = blockIdx.x * 256 + threadIdx.x;
    float mx = cm[c];
    sbq[c] = mx / (127.f * 128.f);
    sbinv[c] = 127.f / mx;
}

// W1 [n][h][u] -> BT h/l int8 [n][u][h] (transposed, K=h contiguous)
__global__ void cvtB8(const float* __restrict__ W1,
                      const float* __restrict__ sbinv,
                      signed char* __restrict__ bh, signed char* __restrict__ bl) {
    __shared__ float t[64][65];
    int n = blockIdx.x, h0 = blockIdx.y * 64, u0 = blockIdx.z * 64;
    int tid = threadIdx.x;
    int ul = tid & 63;
    #pragma unroll
    for (int i = 0; i < 16; ++i) {
        int hl = i * 4 + (tid >> 6);
        t[hl][ul] = W1[((size_t)n * H_ + h0 + hl) * U_ + u0 + ul];
    }
    __syncthreads();
    #pragma unroll
    for (int i = 0; i < 16; ++i) {
        int ulw = i * 4 + (tid >> 6);
        int hlw = tid & 63;
        float q = t[hlw][ulw] * sbinv[n * 512 + u0 + ulw];
        float hf = rintf(q);
        float lf = rintf((q - hf) * 128.f);
        size_t o = ((size_t)(n * 512 + u0 + ulw)) * 1024 + h0 + hlw;
        bh[o] = (signed char)(int)hf;
        bl[o] = (signed char)(int)lf;
    }
}

// qb[n,b,u] = sum_h query[b,h]*W2[n,h,u] + b1[n,u] + b2[n,u]   (exact fp32)
__global__ void qb_kernel(const float* __restrict__ query,
                          const float* __restrict__ W2,
                          const float* __restrict__ b1,
                          const float* __restrict__ b2,
                          float* __restrict__ qb) {
    int n = blockIdx.x >> 4;
    int b = blockIdx.x & 15;
    __shared__ float q[H_];
    int tid = threadIdx.x;
    q[tid]       = query[b * H_ + tid];
    q[tid + 512] = query[b * H_ + tid + 512];
    __syncthreads();
    const float* w2 = W2 + (size_t)n * H_ * U_ + tid;
    float acc = 0.f;
    #pragma unroll 4
    for (int h = 0; h < H_; ++h) acc += q[h] * w2[(size_t)h * U_];
    acc += b1[n * U_ + tid] + b2[n * U_ + tid];
    qb[(n * B_ + b) * U_ + tid] = acc;
}

// ---------------- main GEMM: int8 3-pass, single i32 accumulator ----------------
// K'=3072 virtual (48 tiles of K=64): t<16 HH, 16-31 H*Blo, 32-47 Alo*Bh.
// acc <<= 7 between segment 1 and 2. BM=BN=256, 8 waves, 4-slot LDS ring.
// ONE phase per K-tile (32 MFMA, 2 barriers) -- halves barrier count vs R5.
#define NT 48
#define SWZ(d) ((d) ^ ((((d) >> 7) & 3) << 4))
#define ASRC(tt) (((tt) < 32) ? Ah8 : Al8)
#define BSRC(tt) ((((tt) >> 4) == 1) ? Bl8 : Bh8)
#define K0B(tt) (((tt) & 15) * 64)
#define STAGE_A(tt, j) gl16i(ASRC(tt) + (size_t)(rowBase + (j)*128 + rT) * 1024 + K0B(tt) + cTb, \
                             lds + ((tt)&3)*32768 + (j)*8192 + tid*16)
#define STAGE_B(tt, j) gl16i(BSRC(tt) + (size_t)(colBase + (j)*128 + rT) * 1024 + K0B(tt) + cTb, \
                             lds + ((tt)&3)*32768 + 16384 + (j)*8192 + tid*16)

__global__ __launch_bounds__(512, 1) void gemm8i(
        const signed char* __restrict__ Ah8, const signed char* __restrict__ Al8,
        const signed char* __restrict__ Bh8, const signed char* __restrict__ Bl8,
        const float* __restrict__ sa, const float* __restrict__ sbq,
        const float* __restrict__ qb, const float* __restrict__ Vw,
        const float* __restrict__ Ww, float* __restrict__ partial) {
    __shared__ signed char lds[131072];   // 4 slots x (A 16KB | B 16KB)
    const int tid = threadIdx.x;
    const int lane = tid & 63;
    const int wid = tid >> 6;
    const int wm = wid >> 2, wn = wid & 3;   // 2 x 4 wave grid
    int bid = blockIdx.x;
    int swz = (bid & 7) * 256 + (bid >> 3);  // XCD swizzle (2048 % 8 == 0)
    int mIdx = swz & 127, nIdx = swz >> 7;
    int rowBase = mIdx * 256, colBase = nIdx * 256;

    // staging decode: linear LDS dst -> swizzled global src (8KB chunk)
    int d0 = tid * 16;
    int d0s = SWZ(d0);
    int rT  = d0s >> 6;       // row 0..127 within chunk
    int cTb = d0s & 63;       // byte col within 64B row

    // fragment ds_read byte offsets (swizzled, slot-relative)
    const int l15 = lane & 15, l4 = lane >> 4;
    int offA[8], offB[4];
    #pragma unroll
    for (int m = 0; m < 8; ++m)
        offA[m] = SWZ((wm * 128 + m * 16 + l15) * 64 + l4 * 16);
    #pragma unroll
    for (int n = 0; n < 4; ++n)
        offB[n] = 16384 + SWZ((wn * 64 + n * 16 + l15) * 64 + l4 * 16);

    i32x4 acc[8][4];
    #pragma unroll
    for (int m = 0; m < 8; ++m)
        #pragma unroll
        for (int n = 0; n < 4; ++n) acc[m][n] = (i32x4){0, 0, 0, 0};

    // prologue: stage tiles 0..2 (12 loads)
    #pragma unroll
    for (int tt = 0; tt < 3; ++tt) {
        STAGE_A(tt, 0); STAGE_A(tt, 1);
        STAGE_B(tt, 0); STAGE_B(tt, 1);
    }
    asm volatile("s_waitcnt vmcnt(8)" ::: "memory");   // tile 0 resident
    __builtin_amdgcn_s_barrier();

    #pragma unroll 1
    for (int t = 0; t < NT; ++t) {
        if (t == 16) {   // HH pass done over full K: scale by 128 before HL/LH
            #pragma unroll
            for (int m = 0; m < 8; ++m)
                #pragma unroll
                for (int n = 0; n < 4; ++n) acc[m][n] = acc[m][n] << 7;
        }
        const signed char* slot = lds + (t & 3) * 32768;
        i32x4 bf[4], af[8];
        // single phase: all 12 ds_reads + 4 stages, 1 barrier, 32 MFMA, 1 barrier
        #pragma unroll
        for (int n = 0; n < 4; ++n) bf[n] = *(const i32x4*)(slot + offB[n]);
        #pragma unroll
        for (int m = 0; m < 8; ++m) af[m] = *(const i32x4*)(slot + offA[m]);
        if (t <= NT - 4) {
            STAGE_A(t + 3, 0); STAGE_A(t + 3, 1);
            STAGE_B(t + 3, 0); STAGE_B(t + 3, 1);
        }
        __builtin_amdgcn_s_barrier();
        asm volatile("s_waitcnt lgkmcnt(0)" ::: "memory");
        __builtin_amdgcn_s_setprio(1);
        #pragma unroll
        for (int m = 0; m < 8; ++m)
            #pragma unroll
            for (int n = 0; n < 4; ++n)
                acc[m][n] = __builtin_amdgcn_mfma_i32_16x16x64_i8(af[m], bf[n], acc[m][n], 0, 0, 0);
        __builtin_amdgcn_s_setprio(0);
        if (t < NT - 3)       asm volatile("s_waitcnt vmcnt(8)" ::: "memory");
        else if (t == NT - 3) asm volatile("s_waitcnt vmcnt(4)" ::: "memory");
        else if (t == NT - 2) asm volatile("s_waitcnt vmcnt(0)" ::: "memory");
        __builtin_amdgcn_s_barrier();
    }

    // epilogue: Cf = acc*sa*sbq; tanh + Vw*Ww row-reduce; cross-wave LDS reduce
    __syncthreads();
    int hd = colBase >> 9;
    int b = rowBase >> 11;
    float wwn = Ww[hd];
    float qv[4], vw[4], sbv[4];
    #pragma unroll
    for (int n = 0; n < 4; ++n) {
        int col = colBase + wn * 64 + n * 16 + l15;
        int u = col & 511;
        qv[n] = qb[((size_t)hd * B_ + b) * U_ + u];
        vw[n] = Vw[hd * U_ + u] * wwn;
        sbv[n] = sbq[col];
    }
    float* red = (float*)lds;   // [4 wn][256 rows]
    #pragma unroll
    for (int m = 0; m < 8; ++m) {
        float sav[4];
        #pragma unroll
        for (int r = 0; r < 4; ++r)
            sav[r] = sa[rowBase + wm * 128 + m * 16 + l4 * 4 + r];
        #pragma unroll
        for (int r = 0; r < 4; ++r) {
            float p = 0.f;
            #pragma unroll
            for (int n = 0; n < 4; ++n)
                p += vw[n] * fast_tanh((float)acc[m][n][r] * sav[r] * sbv[n] + qv[n]);
            p += __shfl_xor(p, 1);
            p += __shfl_xor(p, 2);
            p += __shfl_xor(p, 4);
            p += __shfl_xor(p, 8);
            if (l15 == 0)
                red[wn * 256 + wm * 128 + m * 16 + l4 * 4 + r] = p;
        }
    }
    __syncthreads();
    if (tid < 256) {
        float s = red[tid] + red[256 + tid] + red[512 + tid] + red[768 + tid];
        partial[(size_t)nIdx * M_ + rowBase + tid] = s;
    }
}

// ---------------- fallback fp32 GEMM (if ws too small) ----------------
__global__ __launch_bounds__(256, 2) void gemm_score(
        const float* __restrict__ values,
        const float* __restrict__ W1,
        const float* __restrict__ qb,
        const float* __restrict__ Vw,
        const float* __restrict__ Ww,
        float* __restrict__ partial) {
    __shared__ float As[16][128 + 4];
    __shared__ float Bs[16][128 + 4];
    int tid = threadIdx.x;
    int tx = tid & 15, ty = tid >> 4;
    int rowBase = blockIdx.x * 128;
    int colBase = blockIdx.y * 128;
    int n = colBase >> 9;
    int u0 = colBase & 511;
    int b = rowBase >> 11;
    float acc[8][8];
    #pragma unroll
    for (int i = 0; i < 8; ++i)
        #pragma unroll
        for (int j = 0; j < 8; ++j) acc[i][j] = 0.f;
    const float* Ag = values + (size_t)rowBase * H_;
    const float* Bg = W1 + (size_t)n * H_ * U_ + u0;
    for (int k0 = 0; k0 < H_; k0 += 16) {
        #pragma unroll
        for (int r = 0; r < 2; ++r) {
            int idx = tid + r * 256;
            int arow = idx >> 2, aqc = idx & 3;
            float4 v = *(const float4*)(Ag + (size_t)arow * H_ + k0 + aqc * 4);
            As[aqc * 4 + 0][arow] = v.x;
            As[aqc * 4 + 1][arow] = v.y;
            As[aqc * 4 + 2][arow] = v.z;
            As[aqc * 4 + 3][arow] = v.w;
        }
        #pragma unroll
        for (int r = 0; r < 2; ++r) {
            int idx = tid + r * 256;
            int bk = idx >> 5, bqc = idx & 31;
            float4 v = *(const float4*)(Bg + (size_t)(k0 + bk) * U_ + bqc * 4);
            *(float4*)&Bs[bk][bqc * 4] = v;
        }
        __syncthreads();
        #pragma unroll
        for (int k = 0; k < 16; ++k) {
            float4 a0 = *(const float4*)&As[k][ty * 8];
            float4 a1 = *(const float4*)&As[k][ty * 8 + 4];
            float4 b0 = *(const float4*)&Bs[k][tx * 8];
            float4 b1v = *(const float4*)&Bs[k][tx * 8 + 4];
            float av[8] = {a0.x, a0.y, a0.z, a0.w, a1.x, a1.y, a1.z, a1.w};
            float bv[8] = {b0.x, b0.y, b0.z, b0.w, b1v.x, b1v.y, b1v.z, b1v.w};
            #pragma unroll
            for (int i = 0; i < 8; ++i)
                #pragma unroll
                for (int j = 0; j < 8; ++j)
                    acc[i][j] = fmaf(av[i], bv[j], acc[i][j]);
        }
        __syncthreads();
    }
    float qbv[8], vwv[8];
    #pragma unroll
    for (int j = 0; j < 8; ++j) {
        int u = u0 + tx * 8 + j;
        qbv[j] = qb[(n * B_ + b) * U_ + u];
        vwv[j] = Vw[n * U_ + u];
    }
    float wwn = Ww[n];
    #pragma unroll
    for (int i = 0; i < 8; ++i) {
        float p = 0.f;
        #pragma unroll
        for (int j = 0; j < 8; ++j)
            p += vwv[j] * fast_tanh(acc[i][j] + qbv[j]);
        p += __shfl_xor(p, 1);
        p += __shfl_xor(p, 2);
        p += __shfl_xor(p, 4);
        p += __shfl_xor(p, 8);
        if (tx == 0)
            partial[(size_t)blockIdx.y * M_ + rowBase + ty * 8 + i] = wwn * p;
    }
}

// ---------------- tail kernels ----------------
__global__ void reduce_score(const float* __restrict__ partial,
                             float* __restrict__ score, int nparts) {
    int row = blockIdx.x * blockDim.x + threadIdx.x;
    float s = 0.f;
    for (int ct = 0; ct < nparts; ++ct) s += partial[(size_t)ct * M_ + row];
    score[row] = s;
}

__global__ __launch_bounds__(1024) void topk_kernel(
        const float* __restrict__ score,
        const float* __restrict__ Vb,
        const float* __restrict__ Ww,
        const float* __restrict__ Wb,
        float* __restrict__ out_masked,
        float* __restrict__ w_un) {
    __shared__ float sc[S_];
    __shared__ float srt[S_];
    __shared__ int cnt_gt;
    int b = blockIdx.x;
    int tid = threadIdx.x;
    float cst = Wb[0];
    #pragma unroll
    for (int n2 = 0; n2 < NH; ++n2) cst += Ww[n2] * Vb[n2];
    for (int s = tid; s < S_; s += 1024) {
        float v = score[b * S_ + s] + cst;
        sc[s] = v; srt[s] = v;
    }
    if (tid == 0) cnt_gt = 0;
    __syncthreads();
    for (int k = 2; k <= S_; k <<= 1) {
        for (int j = k >> 1; j >= 1; j >>= 1) {
            int i = ((tid & ~(j - 1)) << 1) | (tid & (j - 1));
            int p = i | j;
            float a = srt[i], c2 = srt[p];
            if (((i & k) == 0) ? (a > c2) : (a < c2)) { srt[i] = c2; srt[p] = a; }
            __syncthreads();
        }
    }
    float T = srt[S_ - TOPK];
    int c = 0;
    for (int s = tid; s < S_; s += 1024) c += (sc[s] > T);
    atomicAdd(&cnt_gt, c);
    __syncthreads();
    int need_eq = TOPK - cnt_gt;
    for (int s = tid; s < S_; s += 1024) {
        float v = sc[s];
        bool sel = (v > T);
        if (v == T) {
            int rank = 0;
            for (int t2 = 0; t2 < s; ++t2) rank += (sc[t2] == T);
            sel = (rank < need_eq);
        }
        float m = sel ? v : 0.f;
        out_masked[b * S_ + s] = m;
        w_un[b * S_ + s] = 1.f / (1.f + __expf(-m));
    }
}

__global__ void norm_w(const float* __restrict__ w_un, float* __restrict__ out_w) {
    int s = blockIdx.x * blockDim.x + threadIdx.x;
    float d = 0.f;
    #pragma unroll
    for (int b = 0; b < B_; ++b) d += w_un[b * S_ + s];
    float inv = 1.f / d;
    #pragma unroll
    for (int b = 0; b < B_; ++b) out_w[b * S_ + s] = w_un[b * S_ + s] * inv;
}

// context partials from int8 values (v ~= sa*(h + l/128)): 64MB vs 128MB read
__global__ void ctx_partial_i8(const signed char* __restrict__ h8,
                               const signed char* __restrict__ l8,
                               const float* __restrict__ sa,
                               const float* __restrict__ w,
                               float* __restrict__ pctx) {
    int bb = blockIdx.x;
    int h = blockIdx.y * 256 + threadIdx.x;
    int s0 = blockIdx.z * 256;
    __shared__ float ws[256], wsl[256];
    {
        int s = threadIdx.x;
        float wv = w[bb * S_ + s0 + s];
        float sv = sa[bb * S_ + s0 + s];
        ws[s] = wv * sv;
        wsl[s] = wv * sv * (1.f / 128.f);
    }
    __syncthreads();
    const signed char* hp = h8 + (size_t)(bb * S_ + s0) * H_ + h;
    const signed char* lp = l8 + (size_t)(bb * S_ + s0) * H_ + h;
    float acc = 0.f;
    #pragma unroll 4
    for (int s = 0; s < 256; ++s) {
        acc += ws[s] * (float)hp[(size_t)s * H_];
        acc += wsl[s] * (float)lp[(size_t)s * H_];
    }
    pctx[((size_t)blockIdx.z * B_ + bb) * H_ + h] = acc;
}

__global__ void ctx_partial_f32(const float* __restrict__ values,
                                const float* __restrict__ w,
                                float* __restrict__ pctx) {
    int bb = blockIdx.x;
    int h = blockIdx.y * 256 + threadIdx.x;
    int s0 = blockIdx.z * 256;
    __shared__ float wrow[256];
    wrow[threadIdx.x] = w[bb * S_ + s0 + threadIdx.x];
    __syncthreads();
    const float* vp = values + (size_t)(bb * S_ + s0) * H_ + h;
    float acc = 0.f;
    #pragma unroll 4
    for (int s = 0; s < 256; ++s) acc += wrow[s] * vp[(size_t)s * H_];
    pctx[((size_t)blockIdx.z * B_ + bb) * H_ + h] = acc;
}

__global__ void ctx_reduce(const float* __restrict__ pctx,
                           float* __restrict__ out_ctx) {
    int i = blockIdx.x * blockDim.x + threadIdx.x;
    float s = 0.f;
    #pragma unroll
    for (int z = 0; z < 8; ++z) s += pctx[(size_t)z * B_ * H_ + i];
    out_ctx[i] = s;
}

extern "C" void kernel_launch(void* const* d_in, const int* in_sizes, int n_in,
                              void* d_out, int out_size, void* d_ws, size_t ws_size,
                              hipStream_t stream) {
    const float* query = (const float*)d_in[0];
    const float* values = (const float*)d_in[1];
    const float* W1 = (const float*)d_in[2];
    const float* b1 = (const float*)d_in[3];
    const float* W2 = (const float*)d_in[4];
    const float* b2 = (const float*)d_in[5];
    const float* Vw = (const float*)d_in[6];
    const float* Vb = (const float*)d_in[7];
    const float* Ww = (const float*)d_in[8];
    const float* Wb = (const float*)d_in[9];

    float* ws = (float*)d_ws;
    float* qb      = ws;                     // 65536
    float* partial = qb + 65536;             // 1048576
    float* score   = partial + 1048576;      // 32768
    float* w_un    = score + 32768;          // 32768
    float* pctx    = w_un + 32768;           // 131072
    float* sa      = pctx + 131072;          // 32768
    float* sbq     = sa + 32768;             // 4096
    float* sbinv   = sbq + 4096;             // 4096
    float* colmax  = sbinv + 4096;           // 4096
    signed char* Ah8 = (signed char*)(colmax + 4096);  // 32 MB
    signed char* Al8 = Ah8 + (size_t)M_ * H_;          // 32 MB
    signed char* Bh8 = Al8 + (size_t)M_ * H_;          // 4 MB
    signed char* Bl8 = Bh8 + (size_t)NC * H_;          // 4 MB
    size_t needed = (size_t)((char*)(Bl8 + (size_t)NC * H_) - (char*)d_ws);

    float* out_ctx    = (float*)d_out;       // 16384
    float* out_w      = out_ctx + 16384;     // 32768
    float* out_masked = out_w + 32768;       // 32768

    qb_kernel<<<dim3(NH * B_), 512, 0, stream>>>(query, W2, b1, b2, qb);
    if (ws_size >= needed) {
        cvtA<<<dim3(8192), 256, 0, stream>>>(values, Ah8, Al8, sa);
        colmax_init<<<dim3(16), 256, 0, stream>>>(colmax);
        colmax_kernel<<<dim3(NH, 16), 512, 0, stream>>>(W1, colmax);
        colmax_fin<<<dim3(16), 256, 0, stream>>>(colmax, sbq, sbinv);
        cvtB8<<<dim3(NH, 16, 8), 256, 0, stream>>>(W1, sbinv, Bh8, Bl8);
        gemm8i<<<dim3(2048), 512, 0, stream>>>(Ah8, Al8, Bh8, Bl8, sa, sbq,
                                               qb, Vw, Ww, partial);
        reduce_score<<<128, 256, 0, stream>>>(partial, score, 16);
        topk_kernel<<<16, 1024, 0, stream>>>(score, Vb, Ww, Wb, out_masked, w_un);
        norm_w<<<8, 256, 0, stream>>>(w_un, out_w);
        ctx_partial_i8<<<dim3(16, 4, 8), 256, 0, stream>>>(Ah8, Al8, sa, out_w, pctx);
    } else {
        gemm_score<<<dim3(256, 32), 256, 0, stream>>>(values, W1, qb, Vw, Ww, partial);
        reduce_score<<<128, 256, 0, stream>>>(partial, score, 32);
        topk_kernel<<<16, 1024, 0, stream>>>(score, Vb, Ww, Wb, out_masked, w_un);
        norm_w<<<8, 256, 0, stream>>>(w_un, out_w);
        ctx_partial_f32<<<dim3(16, 4, 8), 256, 0, stream>>>(values, out_w, pctx);
    }
    ctx_reduce<<<64, 256, 0, stream>>>(pctx, out_ctx);
}

// Round 8
// 692.441 us; speedup vs baseline: 2.9383x; 1.0227x over previous
//
#include <hip/hip_runtime.h>
#include <hip/hip_bf16.h>

#define B_ 16
#define S_ 2048
#define H_ 1024
#define U_ 512
#define NH 8
#define TOPK 100

#define M_ (B_*S_)      // 32768 rows (b,s)
#define NC (NH*U_)      // 4096 cols (n,u)

typedef int i32x4 __attribute__((ext_vector_type(4)));

__device__ __forceinline__ float fast_tanh(float x) {
    float e = __expf(2.f * x);
    return (e - 1.f) / (e + 1.f);
}

__device__ __forceinline__ void gl16i(const signed char* g, signed char* l) {
    __builtin_amdgcn_global_load_lds(
        (const __attribute__((address_space(1))) void*)g,
        (__attribute__((address_space(3))) void*)l, 16, 0, 0);
}

// ---------------- prep: int8 two-level quantization ----------------
// values: one wave per row; x ~= sa*(h + l/128), h,l in [-127,127]/[-64,64]
__global__ void cvtA(const float* __restrict__ v,
                     signed char* __restrict__ h8,
                     signed char* __restrict__ l8,
                     float* __restrict__ sa) {
    int row = blockIdx.x * 4 + (threadIdx.x >> 6);
    int l = threadIdx.x & 63;
    const float4* r4 = (const float4*)(v + (size_t)row * 1024);
    float4 x[4];
    float mx = 0.f;
    #pragma unroll
    for (int c = 0; c < 4; ++c) {
        x[c] = r4[l * 4 + c];
        mx = fmaxf(mx, fmaxf(fmaxf(fabsf(x[c].x), fabsf(x[c].y)),
                             fmaxf(fabsf(x[c].z), fabsf(x[c].w))));
    }
    #pragma unroll
    for (int d = 1; d < 64; d <<= 1) mx = fmaxf(mx, __shfl_xor(mx, d));
    float inv = 127.f / mx;
    int wh[4], wl[4];
    #pragma unroll
    for (int c = 0; c < 4; ++c) {
        float xs[4] = {x[c].x, x[c].y, x[c].z, x[c].w};
        unsigned ph = 0, pl = 0;
        #pragma unroll
        for (int j = 0; j < 4; ++j) {
            float y = xs[j] * inv;
            float hf = rintf(y);
            float lf = rintf((y - hf) * 128.f);
            ph |= ((unsigned)((int)hf) & 0xffu) << (8 * j);
            pl |= ((unsigned)((int)lf) & 0xffu) << (8 * j);
        }
        wh[c] = (int)ph; wl[c] = (int)pl;
    }
    *(int4*)(h8 + (size_t)row * 1024 + l * 16) = make_int4(wh[0], wh[1], wh[2], wh[3]);
    *(int4*)(l8 + (size_t)row * 1024 + l * 16) = make_int4(wl[0], wl[1], wl[2], wl[3]);
    if (l == 0) sa[row] = mx / 127.f;
}

// ---- coalesced per-column max of |W1| via atomicMax on uint ----
__global__ void colmax_init(float* __restrict__ cm) {
    cm[blockIdx.x * 256 + threadIdx.x] = 0.f;
}
__global__ void colmax_kernel(const float* __restrict__ W1, float* __restrict__ cm) {
    int n = blockIdx.x, h0 = blockIdx.y * 64, u = threadIdx.x;  // 512 threads
    const float* p = W1 + ((size_t)n * H_ + h0) * U_ + u;
    float mx = 0.f;
    #pragma unroll 8
    for (int h = 0; h < 64; ++h) mx = fmaxf(mx, fabsf(p[(size_t)h * U_]));
    atomicMax((unsigned*)(cm + n * U_ + u), __float_as_uint(mx));
}
__global__ void colmax_fin(const float* __restrict__ cm,
                           float* __restrict__ sbq, float* __restrict__ sbinv) {
    int c = blockIdx.x * 256 + threadIdx.x;
    float mx = cm[c];
    sbq[c] = mx / (127.f * 128.f);
    sbinv[c] = 127.f / mx;
}

// W1 [n][h][u] -> BT h/l int8 [n][u][h] (transposed, K=h contiguous)
__global__ void cvtB8(const float* __restrict__ W1,
                      const float* __restrict__ sbinv,
                      signed char* __restrict__ bh, signed char* __restrict__ bl) {
    __shared__ float t[64][65];
    int n = blockIdx.x, h0 = blockIdx.y * 64, u0 = blockIdx.z * 64;
    int tid = threadIdx.x;
    int ul = tid & 63;
    #pragma unroll
    for (int i = 0; i < 16; ++i) {
        int hl = i * 4 + (tid >> 6);
        t[hl][ul] = W1[((size_t)n * H_ + h0 + hl) * U_ + u0 + ul];
    }
    __syncthreads();
    #pragma unroll
    for (int i = 0; i < 16; ++i) {
        int ulw = i * 4 + (tid >> 6);
        int hlw = tid & 63;
        float q = t[hlw][ulw] * sbinv[n * 512 + u0 + ulw];
        float hf = rintf(q);
        float lf = rintf((q - hf) * 128.f);
        size_t o = ((size_t)(n * 512 + u0 + ulw)) * 1024 + h0 + hlw;
        bh[o] = (signed char)(int)hf;
        bl[o] = (signed char)(int)lf;
    }
}

// qb[n,b,u] = sum_h query[b,h]*W2[n,h,u] + b1[n,u] + b2[n,u]   (exact fp32)
__global__ void qb_kernel(const float* __restrict__ query,
                          const float* __restrict__ W2,
                          const float* __restrict__ b1,
                          const float* __restrict__ b2,
                          float* __restrict__ qb) {
    int n = blockIdx.x >> 4;
    int b = blockIdx.x & 15;
    __shared__ float q[H_];
    int tid = threadIdx.x;
    q[tid]       = query[b * H_ + tid];
    q[tid + 512] = query[b * H_ + tid + 512];
    __syncthreads();
    const float* w2 = W2 + (size_t)n * H_ * U_ + tid;
    float acc = 0.f;
    #pragma unroll 4
    for (int h = 0; h < H_; ++h) acc += q[h] * w2[(size_t)h * U_];
    acc += b1[n * U_ + tid] + b2[n * U_ + tid];
    qb[(n * B_ + b) * U_ + tid] = acc;
}

// ---------------- main GEMM: int8 3-pass, reg-double-buffered pipeline ----------------
// K'=3072 virtual (48 tiles of K=64): t<16 HH, 16-31 H*Blo, 32-47 Alo*Bh.
// acc <<= 7 between segment 1 and 2. BM=BN=256, 8 waves, 4-slot LDS ring.
// Per tile: read bf(t)+af(t+1) -> stages(t+3) -> lgkmcnt(8) -> 32 MFMA (regs) ->
// vmcnt(4) -> barrier. A-frags double-buffered so MFMA(t) overlaps reads(t+1).
#define NT 48
#define SWZ(d) ((d) ^ ((((d) >> 7) & 3) << 4))
#define ASRC(tt) (((tt) < 32) ? Ah8 : Al8)
#define BSRC(tt) ((((tt) >> 4) == 1) ? Bl8 : Bh8)
#define K0B(tt) (((tt) & 15) * 64)
#define STAGE_A(tt, j) gl16i(ASRC(tt) + (size_t)(rowBase + (j)*128 + rT) * 1024 + K0B(tt) + cTb, \
                             lds + ((tt)&3)*32768 + (j)*8192 + tid*16)
#define STAGE_B(tt, j) gl16i(BSRC(tt) + (size_t)(colBase + (j)*128 + rT) * 1024 + K0B(tt) + cTb, \
                             lds + ((tt)&3)*32768 + 16384 + (j)*8192 + tid*16)

#define ITER(T, AC, AN) do {                                                  \
    if ((T) == 16) {  /* HH done over full K: scale before HL/LH passes */    \
        _Pragma("unroll") for (int m = 0; m < 8; ++m)                         \
          _Pragma("unroll") for (int n = 0; n < 4; ++n)                       \
            acc[m][n] = acc[m][n] << 7;                                       \
    }                                                                         \
    {   /* bf(T) reads FIRST (oldest in lgkm FIFO) */                         \
        const signed char* sb_ = lds + ((T) & 3) * 32768;                     \
        _Pragma("unroll") for (int n = 0; n < 4; ++n)                         \
            bf[n] = *(const i32x4*)(sb_ + offB[n]);                           \
    }                                                                         \
    __builtin_amdgcn_sched_barrier(0);                                        \
    if ((T) + 1 < NT) {  /* af(T+1) prefetch into other buffer */             \
        const signed char* sa_ = lds + (((T) + 1) & 3) * 32768;               \
        _Pragma("unroll") for (int m = 0; m < 8; ++m)                         \
            AN[m] = *(const i32x4*)(sa_ + offA[m]);                           \
    }                                                                         \
    if ((T) <= NT - 4) {                                                      \
        STAGE_A((T) + 3, 0); STAGE_A((T) + 3, 1);                             \
        STAGE_B((T) + 3, 0); STAGE_B((T) + 3, 1);                             \
    }                                                                         \
    __builtin_amdgcn_sched_barrier(0);                                        \
    if ((T) < NT - 1) asm volatile("s_waitcnt lgkmcnt(8)" ::: "memory");      \
    else              asm volatile("s_waitcnt lgkmcnt(0)" ::: "memory");      \
    __builtin_amdgcn_sched_barrier(0);                                        \
    __builtin_amdgcn_s_setprio(1);                                            \
    _Pragma("unroll") for (int m = 0; m < 8; ++m)                             \
      _Pragma("unroll") for (int n = 0; n < 4; ++n)                           \
        acc[m][n] = __builtin_amdgcn_mfma_i32_16x16x64_i8(AC[m], bf[n], acc[m][n], 0, 0, 0); \
    __builtin_amdgcn_s_setprio(0);                                            \
    __builtin_amdgcn_sched_barrier(0);                                        \
    if ((T) <= NT - 4)      asm volatile("s_waitcnt vmcnt(4)" ::: "memory");  \
    else if ((T) == NT - 3) asm volatile("s_waitcnt vmcnt(0)" ::: "memory");  \
    __builtin_amdgcn_s_barrier();                                             \
  } while (0)

__global__ __launch_bounds__(512, 1) void gemm8i(
        const signed char* __restrict__ Ah8, const signed char* __restrict__ Al8,
        const signed char* __restrict__ Bh8, const signed char* __restrict__ Bl8,
        const float* __restrict__ sa, const float* __restrict__ sbq,
        const float* __restrict__ qb, const float* __restrict__ Vw,
        const float* __restrict__ Ww, float* __restrict__ partial) {
    __shared__ signed char lds[131072];   // 4 slots x (A 16KB | B 16KB)
    const int tid = threadIdx.x;
    const int lane = tid & 63;
    const int wid = tid >> 6;
    const int wm = wid >> 2, wn = wid & 3;   // 2 x 4 wave grid
    int bid = blockIdx.x;
    int swz = (bid & 7) * 256 + (bid >> 3);  // XCD swizzle (2048 % 8 == 0)
    int mIdx = swz & 127, nIdx = swz >> 7;
    int rowBase = mIdx * 256, colBase = nIdx * 256;

    // staging decode: linear LDS dst -> swizzled global src (8KB chunk)
    int d0 = tid * 16;
    int d0s = SWZ(d0);
    int rT  = d0s >> 6;       // row 0..127 within chunk
    int cTb = d0s & 63;       // byte col within 64B row

    // fragment ds_read byte offsets (swizzled, slot-relative)
    const int l15 = lane & 15, l4 = lane >> 4;
    int offA[8], offB[4];
    #pragma unroll
    for (int m = 0; m < 8; ++m)
        offA[m] = SWZ((wm * 128 + m * 16 + l15) * 64 + l4 * 16);
    #pragma unroll
    for (int n = 0; n < 4; ++n)
        offB[n] = 16384 + SWZ((wn * 64 + n * 16 + l15) * 64 + l4 * 16);

    i32x4 acc[8][4];
    #pragma unroll
    for (int m = 0; m < 8; ++m)
        #pragma unroll
        for (int n = 0; n < 4; ++n) acc[m][n] = (i32x4){0, 0, 0, 0};

    // prologue: stage tiles 0..2; wait tiles 0,1 resident; preload af(0)
    #pragma unroll
    for (int tt = 0; tt < 3; ++tt) {
        STAGE_A(tt, 0); STAGE_A(tt, 1);
        STAGE_B(tt, 0); STAGE_B(tt, 1);
    }
    asm volatile("s_waitcnt vmcnt(4)" ::: "memory");
    __builtin_amdgcn_s_barrier();

    i32x4 afE[8], afO[8], bf[4];
    #pragma unroll
    for (int m = 0; m < 8; ++m) afE[m] = *(const i32x4*)(lds + offA[m]);

    #pragma unroll 1
    for (int tt = 0; tt < NT; tt += 2) {
        ITER(tt, afE, afO);
        ITER(tt + 1, afO, afE);
    }

    // epilogue: Cf = acc*sa*sbq; tanh + Vw*Ww row-reduce; cross-wave LDS reduce
    __syncthreads();
    int hd = colBase >> 9;
    int b = rowBase >> 11;
    float wwn = Ww[hd];
    float qv[4], vw[4], sbv[4];
    #pragma unroll
    for (int n = 0; n < 4; ++n) {
        int col = colBase + wn * 64 + n * 16 + l15;
        int u = col & 511;
        qv[n] = qb[((size_t)hd * B_ + b) * U_ + u];
        vw[n] = Vw[hd * U_ + u] * wwn;
        sbv[n] = sbq[col];
    }
    float* red = (float*)lds;   // [4 wn][256 rows]
    #pragma unroll
    for (int m = 0; m < 8; ++m) {
        float sav[4];
        #pragma unroll
        for (int r = 0; r < 4; ++r)
            sav[r] = sa[rowBase + wm * 128 + m * 16 + l4 * 4 + r];
        #pragma unroll
        for (int r = 0; r < 4; ++r) {
            float p = 0.f;
            #pragma unroll
            for (int n = 0; n < 4; ++n)
                p += vw[n] * fast_tanh((float)acc[m][n][r] * sav[r] * sbv[n] + qv[n]);
            p += __shfl_xor(p, 1);
            p += __shfl_xor(p, 2);
            p += __shfl_xor(p, 4);
            p += __shfl_xor(p, 8);
            if (l15 == 0)
                red[wn * 256 + wm * 128 + m * 16 + l4 * 4 + r] = p;
        }
    }
    __syncthreads();
    if (tid < 256) {
        float s = red[tid] + red[256 + tid] + red[512 + tid] + red[768 + tid];
        partial[(size_t)nIdx * M_ + rowBase + tid] = s;
    }
}

// ---------------- fallback fp32 GEMM (if ws too small) ----------------
__global__ __launch_bounds__(256, 2) void gemm_score(
        const float* __restrict__ values,
        const float* __restrict__ W1,
        const float* __restrict__ qb,
        const float* __restrict__ Vw,
        const float* __restrict__ Ww,
        float* __restrict__ partial) {
    __shared__ float As[16][128 + 4];
    __shared__ float Bs[16][128 + 4];
    int tid = threadIdx.x;
    int tx = tid & 15, ty = tid >> 4;
    int rowBase = blockIdx.x * 128;
    int colBase = blockIdx.y * 128;
    int n = colBase >> 9;
    int u0 = colBase & 511;
    int b = rowBase >> 11;
    float acc[8][8];
    #pragma unroll
    for (int i = 0; i < 8; ++i)
        #pragma unroll
        for (int j = 0; j < 8; ++j) acc[i][j] = 0.f;
    const float* Ag = values + (size_t)rowBase * H_;
    const float* Bg = W1 + (size_t)n * H_ * U_ + u0;
    for (int k0 = 0; k0 < H_; k0 += 16) {
        #pragma unroll
        for (int r = 0; r < 2; ++r) {
            int idx = tid + r * 256;
            int arow = idx >> 2, aqc = idx & 3;
            float4 v = *(const float4*)(Ag + (size_t)arow * H_ + k0 + aqc * 4);
            As[aqc * 4 + 0][arow] = v.x;
            As[aqc * 4 + 1][arow] = v.y;
            As[aqc * 4 + 2][arow] = v.z;
            As[aqc * 4 + 3][arow] = v.w;
        }
        #pragma unroll
        for (int r = 0; r < 2; ++r) {
            int idx = tid + r * 256;
            int bk = idx >> 5, bqc = idx & 31;
            float4 v = *(const float4*)(Bg + (size_t)(k0 + bk) * U_ + bqc * 4);
            *(float4*)&Bs[bk][bqc * 4] = v;
        }
        __syncthreads();
        #pragma unroll
        for (int k = 0; k < 16; ++k) {
            float4 a0 = *(const float4*)&As[k][ty * 8];
            float4 a1 = *(const float4*)&As[k][ty * 8 + 4];
            float4 b0 = *(const float4*)&Bs[k][tx * 8];
            float4 b1v = *(const float4*)&Bs[k][tx * 8 + 4];
            float av[8] = {a0.x, a0.y, a0.z, a0.w, a1.x, a1.y, a1.z, a1.w};
            float bv[8] = {b0.x, b0.y, b0.z, b0.w, b1v.x, b1v.y, b1v.z, b1v.w};
            #pragma unroll
            for (int i = 0; i < 8; ++i)
                #pragma unroll
                for (int j = 0; j < 8; ++j)
                    acc[i][j] = fmaf(av[i], bv[j], acc[i][j]);
        }
        __syncthreads();
    }
    float qbv[8], vwv[8];
    #pragma unroll
    for (int j = 0; j < 8; ++j) {
        int u = u0 + tx * 8 + j;
        qbv[j] = qb[(n * B_ + b) * U_ + u];
        vwv[j] = Vw[n * U_ + u];
    }
    float wwn = Ww[n];
    #pragma unroll
    for (int i = 0; i < 8; ++i) {
        float p = 0.f;
        #pragma unroll
        for (int j = 0; j < 8; ++j)
            p += vwv[j] * fast_tanh(acc[i][j] + qbv[j]);
        p += __shfl_xor(p, 1);
        p += __shfl_xor(p, 2);
        p += __shfl_xor(p, 4);
        p += __shfl_xor(p, 8);
        if (tx == 0)
            partial[(size_t)blockIdx.y * M_ + rowBase + ty * 8 + i] = wwn * p;
    }
}

// ---------------- tail kernels ----------------
__global__ void reduce_score(const float* __restrict__ partial,
                             float* __restrict__ score, int nparts) {
    int row = blockIdx.x * blockDim.x + threadIdx.x;
    float s = 0.f;
    for (int ct = 0; ct < nparts; ++ct) s += partial[(size_t)ct * M_ + row];
    score[row] = s;
}

__global__ __launch_bounds__(1024) void topk_kernel(
        const float* __restrict__ score,
        const float* __restrict__ Vb,
        const float* __restrict__ Ww,
        const float* __restrict__ Wb,
        float* __restrict__ out_masked,
        float* __restrict__ w_un) {
    __shared__ float sc[S_];
    __shared__ float srt[S_];
    __shared__ int cnt_gt;
    int b = blockIdx.x;
    int tid = threadIdx.x;
    float cst = Wb[0];
    #pragma unroll
    for (int n2 = 0; n2 < NH; ++n2) cst += Ww[n2] * Vb[n2];
    for (int s = tid; s < S_; s += 1024) {
        float v = score[b * S_ + s] + cst;
        sc[s] = v; srt[s] = v;
    }
    if (tid == 0) cnt_gt = 0;
    __syncthreads();
    for (int k = 2; k <= S_; k <<= 1) {
        for (int j = k >> 1; j >= 1; j >>= 1) {
            int i = ((tid & ~(j - 1)) << 1) | (tid & (j - 1));
            int p = i | j;
            float a = srt[i], c2 = srt[p];
            if (((i & k) == 0) ? (a > c2) : (a < c2)) { srt[i] = c2; srt[p] = a; }
            __syncthreads();
        }
    }
    float T = srt[S_ - TOPK];
    int c = 0;
    for (int s = tid; s < S_; s += 1024) c += (sc[s] > T);
    atomicAdd(&cnt_gt, c);
    __syncthreads();
    int need_eq = TOPK - cnt_gt;
    for (int s = tid; s < S_; s += 1024) {
        float v = sc[s];
        bool sel = (v > T);
        if (v == T) {
            int rank = 0;
            for (int t2 = 0; t2 < s; ++t2) rank += (sc[t2] == T);
            sel = (rank < need_eq);
        }
        float m = sel ? v : 0.f;
        out_masked[b * S_ + s] = m;
        w_un[b * S_ + s] = 1.f / (1.f + __expf(-m));
    }
}

__global__ void norm_w(const float* __restrict__ w_un, float* __restrict__ out_w) {
    int s = blockIdx.x * blockDim.x + threadIdx.x;
    float d = 0.f;
    #pragma unroll
    for (int b = 0; b < B_; ++b) d += w_un[b * S_ + s];
    float inv = 1.f / d;
    #pragma unroll
    for (int b = 0; b < B_; ++b) out_w[b * S_ + s] = w_un[b * S_ + s] * inv;
}

// context partials from int8 values (v ~= sa*(h + l/128)): 64MB vs 128MB read
__global__ void ctx_partial_i8(const signed char* __restrict__ h8,
                               const signed char* __restrict__ l8,
                               const float* __restrict__ sa,
                               const float* __restrict__ w,
                               float* __restrict__ pctx) {
    int bb = blockIdx.x;
    int h = blockIdx.y * 256 + threadIdx.x;
    int s0 = blockIdx.z * 256;
    __shared__ float ws[256], wsl[256];
    {
        int s = threadIdx.x;
        float wv = w[bb * S_ + s0 + s];
        float sv = sa[bb * S_ + s0 + s];
        ws[s] = wv * sv;
        wsl[s] = wv * sv * (1.f / 128.f);
    }
    __syncthreads();
    const signed char* hp = h8 + (size_t)(bb * S_ + s0) * H_ + h;
    const signed char* lp = l8 + (size_t)(bb * S_ + s0) * H_ + h;
    float acc = 0.f;
    #pragma unroll 4
    for (int s = 0; s < 256; ++s) {
        acc += ws[s] * (float)hp[(size_t)s * H_];
        acc += wsl[s] * (float)lp[(size_t)s * H_];
    }
    pctx[((size_t)blockIdx.z * B_ + bb) * H_ + h] = acc;
}

__global__ void ctx_partial_f32(const float* __restrict__ values,
                                const float* __restrict__ w,
                                float* __restrict__ pctx) {
    int bb = blockIdx.x;
    int h = blockIdx.y * 256 + threadIdx.x;
    int s0 = blockIdx.z * 256;
    __shared__ float wrow[256];
    wrow[threadIdx.x] = w[bb * S_ + s0 + threadIdx.x];
    __syncthreads();
    const float* vp = values + (size_t)(bb * S_ + s0) * H_ + h;
    float acc = 0.f;
    #pragma unroll 4
    for (int s = 0; s < 256; ++s) acc += wrow[s] * vp[(size_t)s * H_];
    pctx[((size_t)blockIdx.z * B_ + bb) * H_ + h] = acc;
}

__global__ void ctx_reduce(const float* __restrict__ pctx,
                           float* __restrict__ out_ctx) {
    int i = blockIdx.x * blockDim.x + threadIdx.x;
    float s = 0.f;
    #pragma unroll
    for (int z = 0; z < 8; ++z) s += pctx[(size_t)z * B_ * H_ + i];
    out_ctx[i] = s;
}

extern "C" void kernel_launch(void* const* d_in, const int* in_sizes, int n_in,
                              void* d_out, int out_size, void* d_ws, size_t ws_size,
                              hipStream_t stream) {
    const float* query = (const float*)d_in[0];
    const float* values = (const float*)d_in[1];
    const float* W1 = (const float*)d_in[2];
    const float* b1 = (const float*)d_in[3];
    const float* W2 = (const float*)d_in[4];
    const float* b2 = (const float*)d_in[5];
    const float* Vw = (const float*)d_in[6];
    const float* Vb = (const float*)d_in[7];
    const float* Ww = (const float*)d_in[8];
    const float* Wb = (const float*)d_in[9];

    float* ws = (float*)d_ws;
    float* qb      = ws;                     // 65536
    float* partial = qb + 65536;             // 1048576
    float* score   = partial + 1048576;      // 32768
    float* w_un    = score + 32768;          // 32768
    float* pctx    = w_un + 32768;           // 131072
    float* sa      = pctx + 131072;          // 32768
    float* sbq     = sa + 32768;             // 4096
    float* sbinv   = sbq + 4096;             // 4096
    float* colmax  = sbinv + 4096;           // 4096
    signed char* Ah8 = (signed char*)(colmax + 4096);  // 32 MB
    signed char* Al8 = Ah8 + (size_t)M_ * H_;          // 32 MB
    signed char* Bh8 = Al8 + (size_t)M_ * H_;          // 4 MB
    signed char* Bl8 = Bh8 + (size_t)NC * H_;          // 4 MB
    size_t needed = (size_t)((char*)(Bl8 + (size_t)NC * H_) - (char*)d_ws);

    float* out_ctx    = (float*)d_out;       // 16384
    float* out_w      = out_ctx + 16384;     // 32768
    float* out_masked = out_w + 32768;       // 32768

    qb_kernel<<<dim3(NH * B_), 512, 0, stream>>>(query, W2, b1, b2, qb);
    if (ws_size >= needed) {
        cvtA<<<dim3(8192), 256, 0, stream>>>(values, Ah8, Al8, sa);
        colmax_init<<<dim3(16), 256, 0, stream>>>(colmax);
        colmax_kernel<<<dim3(NH, 16), 512, 0, stream>>>(W1, colmax);
        colmax_fin<<<dim3(16), 256, 0, stream>>>(colmax, sbq, sbinv);
        cvtB8<<<dim3(NH, 16, 8), 256, 0, stream>>>(W1, sbinv, Bh8, Bl8);
        gemm8i<<<dim3(2048), 512, 0, stream>>>(Ah8, Al8, Bh8, Bl8, sa, sbq,
                                               qb, Vw, Ww, partial);
        reduce_score<<<128, 256, 0, stream>>>(partial, score, 16);
        topk_kernel<<<16, 1024, 0, stream>>>(score, Vb, Ww, Wb, out_masked, w_un);
        norm_w<<<8, 256, 0, stream>>>(w_un, out_w);
        ctx_partial_i8<<<dim3(16, 4, 8), 256, 0, stream>>>(Ah8, Al8, sa, out_w, pctx);
    } else {
        gemm_score<<<dim3(256, 32), 256, 0, stream>>>(values, W1, qb, Vw, Ww, partial);
        reduce_score<<<128, 256, 0, stream>>>(partial, score, 32);
        topk_kernel<<<16, 1024, 0, stream>>>(score, Vb, Ww, Wb, out_masked, w_un);
        norm_w<<<8, 256, 0, stream>>>(w_un, out_w);
        ctx_partial_f32<<<dim3(16, 4, 8), 256, 0, stream>>>(values, out_w, pctx);
    }
    ctx_reduce<<<64, 256, 0, stream>>>(pctx, out_ctx);
}